// Round 11
// baseline (360.321 us; speedup 1.0000x reference)
//
#include <hip/hip_runtime.h>

#define BB   4
#define LL   2048
#define DD   512
#define HH   8
#define DH   64
#define BH   32          // B*H
#define KTOP 38
#define NCAND 64         // approx-M candidate pool for exact refinement
#define SCALEF 0.125f    // 1/sqrt(64)

// sparse flash split-K params
#define NSP  16          // key chunks
#define CHK  128         // keys per chunk (LL/NSP)
#define QPAD 48          // queries padded to 3 m-tiles
#define SCS  132         // sc row stride (floats)
#define VST  66          // Vhl row stride (uints)

typedef __attribute__((ext_vector_type(8))) short bf16x8;
typedef __attribute__((ext_vector_type(8))) unsigned short ushort8;
typedef __attribute__((ext_vector_type(4))) float f32x4;

__device__ __forceinline__ ushort f32_to_bf16_rn(float x) {
    unsigned u = __float_as_uint(x);
    u += 0x7fffu + ((u >> 16) & 1u);
    return (ushort)(u >> 16);
}
__device__ __forceinline__ float bf16_to_f32(ushort h) {
    return __uint_as_float(((unsigned)h) << 16);
}
__device__ __forceinline__ unsigned int pack_hl(float x) {
    ushort h = f32_to_bf16_rn(x);
    ushort l = f32_to_bf16_rn(x - bf16_to_f32(h));
    return ((unsigned int)l << 16) | (unsigned int)h;
}

// ---------------------------------------------------------------------------
// Elementwise split: fp32 array -> bf16 hi + lo arrays (layout-preserving).
// ---------------------------------------------------------------------------
__global__ __launch_bounds__(256) void split_x(const float* __restrict__ X,
                                               ushort* __restrict__ XH,
                                               ushort* __restrict__ XL) {
    const size_t c = (size_t)blockIdx.x * 256 + threadIdx.x;
    const float4 v = *(const float4*)&X[c * 4];
    ushort4 h, l;
    h.x = f32_to_bf16_rn(v.x); l.x = f32_to_bf16_rn(v.x - bf16_to_f32(h.x));
    h.y = f32_to_bf16_rn(v.y); l.y = f32_to_bf16_rn(v.y - bf16_to_f32(h.y));
    h.z = f32_to_bf16_rn(v.z); l.z = f32_to_bf16_rn(v.z - bf16_to_f32(h.z));
    h.w = f32_to_bf16_rn(v.w); l.w = f32_to_bf16_rn(v.w - bf16_to_f32(h.w));
    *(ushort4*)&XH[c * 4] = h;
    *(ushort4*)&XL[c * 4] = l;
}

// ---------------------------------------------------------------------------
// Prep: transpose + split 3 weight matrices (Wq,Wk,Wv) into [n][k] bf16 hi/lo.
// ---------------------------------------------------------------------------
__global__ __launch_bounds__(256) void split_wT(const float* __restrict__ W0,
                                                const float* __restrict__ W1,
                                                const float* __restrict__ W2,
                                                ushort* __restrict__ WTH,
                                                ushort* __restrict__ WTL) {
    __shared__ float tile[32][33];
    const int z = blockIdx.z;
    const float* W = (z == 0) ? W0 : (z == 1) ? W1 : W2;
    ushort* oh = WTH + (size_t)z * DD * DD;
    ushort* ol = WTL + (size_t)z * DD * DD;
    const int n0 = blockIdx.x * 32, k0 = blockIdx.y * 32;
    const int t = threadIdx.x;
    const int r = t >> 5, c = t & 31;
    #pragma unroll
    for (int i = 0; i < 4; i++)
        tile[r + i * 8][c] = W[(size_t)(k0 + r + i * 8) * DD + n0 + c];
    __syncthreads();
    #pragma unroll
    for (int i = 0; i < 4; i++) {
        int row = r + i * 8;
        float v = tile[c][row];
        ushort h = f32_to_bf16_rn(v);
        oh[(size_t)(n0 + row) * DD + k0 + c] = h;
        ol[(size_t)(n0 + row) * DD + k0 + c] = f32_to_bf16_rn(v - bf16_to_f32(h));
    }
}

// ---------------------------------------------------------------------------
// FUSED QKV projection GEMM, BK=64, register-double-buffered pipeline:
// next-step A-fragments (VGPR dbuf) and B-stage regs are loaded AFTER the
// post-stage barrier, overlapping the current step's MFMA block (the
// __syncthreads vmcnt(0) drain that serialized loads+MFMA now lands after
// the MFMA has issued). MFMA chain order identical to R10.
// ---------------------------------------------------------------------------
__global__ __launch_bounds__(256) void mfma_gemm_qkv(const ushort* __restrict__ AH,
                                                     const ushort* __restrict__ AL,
                                                     const ushort* __restrict__ BTH,
                                                     const ushort* __restrict__ BTL,
                                                     const float* __restrict__ bq,
                                                     const float* __restrict__ bk,
                                                     const float* __restrict__ bv,
                                                     float* __restrict__ Qp,
                                                     float* __restrict__ Kp,
                                                     float* __restrict__ Vp,
                                                     ushort* __restrict__ KH) {
    __shared__ ushort BHs[64 * 72];
    __shared__ ushort BLs[64 * 72];

    const int t = threadIdx.x;
    const int w = t >> 6, lane = t & 63;
    const int quad = lane >> 4, n16 = lane & 15;
    const int row0 = blockIdx.y * 128;
    const int n0   = blockIdx.x * 64;        // 0..1472
    const int z    = n0 >> 9;                // 0=Q 1=K 2=V
    const int nloc0 = n0 & 511;

    const float* bias = (z == 0) ? bq : (z == 1) ? bk : bv;
    float* Y          = (z == 0) ? Qp : (z == 1) ? Kp : Vp;

    f32x4 acc[2][4] = {};

    size_t arow_off[2];
    #pragma unroll
    for (int mt = 0; mt < 2; mt++)
        arow_off[mt] = (size_t)(row0 + w * 32 + mt * 16 + n16) * DD;

    const size_t bbase = (size_t)z * DD * DD;
    const int srow = t >> 3, sc8 = t & 7;    // B staging map: 2 uint4/thread

    // ---- prologue: load step-0 B stage regs + A frags ----
    uint4 bregH[2], bregL[2];
    #pragma unroll
    for (int i = 0; i < 2; i++) {
        const int row = srow + i * 32;
        const size_t goff = bbase + (size_t)(nloc0 + row) * DD + sc8 * 8;
        bregH[i] = *(const uint4*)&BTH[goff];
        bregL[i] = *(const uint4*)&BTL[goff];
    }
    bf16x8 ah[2][2][2], al[2][2][2];        // [buf][mt][kf]
    #pragma unroll
    for (int mt = 0; mt < 2; mt++)
        #pragma unroll
        for (int kf = 0; kf < 2; kf++) {
            size_t off = arow_off[mt] + kf * 32 + quad * 8;
            ah[0][mt][kf] = *(const bf16x8*)&AH[off];
            al[0][mt][kf] = *(const bf16x8*)&AL[off];
        }

    for (int k = 0; k < 8; k++) {            // k0 = k*64
        const int cur = k & 1, nxt = cur ^ 1;
        // write staged B regs to LDS
        #pragma unroll
        for (int i = 0; i < 2; i++) {
            const int row = srow + i * 32;
            *(uint4*)&BHs[row * 72 + sc8 * 8] = bregH[i];
            *(uint4*)&BLs[row * 72 + sc8 * 8] = bregL[i];
        }
        __syncthreads();

        // prefetch next step (overlaps MFMA below)
        if (k < 7) {
            const int kn = (k + 1) * 64;
            #pragma unroll
            for (int i = 0; i < 2; i++) {
                const int row = srow + i * 32;
                const size_t goff = bbase + (size_t)(nloc0 + row) * DD + kn + sc8 * 8;
                bregH[i] = *(const uint4*)&BTH[goff];
                bregL[i] = *(const uint4*)&BTL[goff];
            }
            #pragma unroll
            for (int mt = 0; mt < 2; mt++)
                #pragma unroll
                for (int kf = 0; kf < 2; kf++) {
                    size_t off = arow_off[mt] + kn + kf * 32 + quad * 8;
                    ah[nxt][mt][kf] = *(const bf16x8*)&AH[off];
                    al[nxt][mt][kf] = *(const bf16x8*)&AL[off];
                }
        }

        // MFMA (same chain order as R10)
        #pragma unroll
        for (int kf = 0; kf < 2; kf++)
            #pragma unroll
            for (int nt = 0; nt < 4; nt++) {
                int boff = (nt * 16 + n16) * 72 + kf * 32 + quad * 8;
                bf16x8 bh = *(const bf16x8*)&BHs[boff];
                bf16x8 bl = *(const bf16x8*)&BLs[boff];
                #pragma unroll
                for (int mt = 0; mt < 2; mt++) {
                    acc[mt][nt] = __builtin_amdgcn_mfma_f32_16x16x32_bf16(ah[cur][mt][kf], bh, acc[mt][nt], 0, 0, 0);
                    acc[mt][nt] = __builtin_amdgcn_mfma_f32_16x16x32_bf16(ah[cur][mt][kf], bl, acc[mt][nt], 0, 0, 0);
                    acc[mt][nt] = __builtin_amdgcn_mfma_f32_16x16x32_bf16(al[cur][mt][kf], bh, acc[mt][nt], 0, 0, 0);
                }
            }
        __syncthreads();
    }

    #pragma unroll
    for (int mt = 0; mt < 2; mt++)
        #pragma unroll
        for (int nt = 0; nt < 4; nt++) {
            const int c = nloc0 + nt * 16 + n16;
            const float bvv = bias[c];
            const int h = c >> 6, dh = c & 63;
            #pragma unroll
            for (int r = 0; r < 4; r++) {
                int R = row0 + w * 32 + mt * 16 + quad * 4 + r;
                int b = R >> 11, l = R & 2047;
                float v = acc[mt][nt][r] + bvv;
                size_t off = (((size_t)(b * HH + h)) * LL + l) * DH + dh;
                Y[off] = v;
                if (z == 1) KH[off] = f32_to_bf16_rn(v);
            }
        }
}

// ---------------------------------------------------------------------------
// Mean phase 1: partial sums. grid (BH, 2, 16); block sums 128 rows.
// ---------------------------------------------------------------------------
__global__ __launch_bounds__(256) void mean_partial(const float* __restrict__ Kp,
                                                    const float* __restrict__ Vp,
                                                    float* __restrict__ partial) {
    __shared__ float red[256];
    const int bh = blockIdx.x;
    const int srcI = blockIdx.y;
    const int z  = blockIdx.z;
    const float* src = srcI ? Vp : Kp;
    const int t = threadIdx.x;
    const int d = t & 63, ch = t >> 6;
    const int l0 = z * 128 + ch * 32;
    float s = 0.f;
    for (int l = l0; l < l0 + 32; l++)
        s += src[((size_t)bh * LL + l) * DH + d];
    red[t] = s;
    __syncthreads();
    if (t < 64)
        partial[((size_t)((bh * 2 + srcI) * 16 + z)) * 64 + t] =
            red[t] + red[t + 64] + red[t + 128] + red[t + 192];
}

// ---------------------------------------------------------------------------
// Mean phase 2: fold 16 partials. grid (BH, 2), 64 thr.
// ---------------------------------------------------------------------------
__global__ __launch_bounds__(64) void mean_reduce(const float* __restrict__ partial,
                                                  float* __restrict__ Kmean,
                                                  float* __restrict__ Vmean) {
    const int bh = blockIdx.x;
    const int srcI = blockIdx.y;
    const int t  = threadIdx.x;
    float s = 0.f;
    #pragma unroll
    for (int z = 0; z < 16; z++)
        s += partial[((size_t)((bh * 2 + srcI) * 16 + z)) * 64 + t];
    float* dst = srcI ? Vmean : Kmean;
    dst[bh * DH + t] = s * (1.0f / LL);
}

// ---------------------------------------------------------------------------
// base[b] = sum_h Vmean[b,h] @ Wo_h + bo  (fp32 exact). Grid (BB), 256 thr.
// ---------------------------------------------------------------------------
__global__ __launch_bounds__(256) void base_kernel(const float* __restrict__ Vmean,
                                                   const float* __restrict__ Wo,
                                                   const float* __restrict__ bo,
                                                   float* __restrict__ BASE) {
    __shared__ float vm[512];
    const int b = blockIdx.x;
    const int t = threadIdx.x;
    vm[t]       = Vmean[b * 512 + t];
    vm[t + 256] = Vmean[b * 512 + t + 256];
    __syncthreads();
    #pragma unroll
    for (int cc = 0; cc < 2; cc++) {
        const int c = cc * 256 + t;
        float s = 0.f;
        for (int k = 0; k < 512; k++) s += vm[k] * Wo[(size_t)k * 512 + c];
        BASE[b * 512 + c] = s + bo[c];
    }
}

// ---------------------------------------------------------------------------
// Broadcast base rows into out. 4096 blocks x 256 thr, float4 each.
// ---------------------------------------------------------------------------
__global__ __launch_bounds__(256) void broadcast_base(const float* __restrict__ BASE,
                                                      float* __restrict__ out) {
    const size_t f = ((size_t)blockIdx.x * 256 + threadIdx.x) * 4;
    const int b = (int)(f >> 20);            // / (2048*512)
    const int c = (int)(f & 511);
    *(float4*)&out[f] = *(const float4*)&BASE[b * 512 + c];
}

// ---------------------------------------------------------------------------
// FUSED combine+scatter: per (bh,q) fold the 16 split-K partials (softmax
// merge), subtract Vmean, and scatter (corr @ Wo_h) into out via atomicAdd.
// ---------------------------------------------------------------------------
__global__ __launch_bounds__(256) void scatter_kernel(const float* __restrict__ OPART,
                                                      const float* __restrict__ MPART,
                                                      const float* __restrict__ LPART,
                                                      const float* __restrict__ Vmean,
                                                      const int* __restrict__ TIDX,
                                                      const float* __restrict__ Wo,
                                                      float* __restrict__ out) {
    __shared__ float cr[64];
    const int q = blockIdx.x, bh = blockIdx.y;
    const int b = bh >> 3, h = bh & 7;
    const int t = threadIdx.x;
    if (t < 64) {
        float m[NSP];
        float mx = -3.4e38f;
        #pragma unroll
        for (int c = 0; c < NSP; c++) {
            m[c] = MPART[((size_t)c * BH + bh) * KTOP + q];
            mx = fmaxf(mx, m[c]);
        }
        float L = 0.f;
        #pragma unroll
        for (int c = 0; c < NSP; c++) {
            m[c] = __expf(m[c] - mx);
            L += m[c] * LPART[((size_t)c * BH + bh) * KTOP + q];
        }
        const float inv = 1.0f / L;
        float o = 0.f;
        #pragma unroll
        for (int c = 0; c < NSP; c++)
            o += m[c] * OPART[(((size_t)c * BH + bh) * KTOP + q) * DH + t];
        cr[t] = o * inv - Vmean[bh * DH + t];
    }
    __syncthreads();
    const int l = TIDX[bh * KTOP + q];
    #pragma unroll
    for (int cc = 0; cc < 2; cc++) {
        const int c = cc * 256 + t;
        float s = 0.f;
        #pragma unroll
        for (int d = 0; d < 64; d++) s += cr[d] * Wo[(size_t)(h * 64 + d) * 512 + c];
        atomicAdd(&out[((size_t)b * LL + l) * DD + c], s);
    }
}

// ---------------------------------------------------------------------------
// Approx M, split-K, register-prefetch pipelined K staging (single stage-reg
// buffer: ds_write consumes regs at issue; reload after barrier overlaps the
// MFMA block). Grid (16, BH, 2). MFMA chain order unchanged.
// ---------------------------------------------------------------------------
__global__ __launch_bounds__(256) void mfma_stats(const float* __restrict__ Qp,
                                                  const ushort* __restrict__ KH,
                                                  const float* __restrict__ Kmean,
                                                  float* __restrict__ MP,
                                                  float* __restrict__ MMD) {
    __shared__ ushort KS[128 * 72];
    __shared__ float  Km[64];

    const int bh = blockIdx.y;
    const int q0 = blockIdx.x * 128;
    const int z  = blockIdx.z;
    const int t    = threadIdx.x;
    const int w    = t >> 6;
    const int lane = t & 63;
    const int quad = lane >> 4;
    const int n16  = lane & 15;
    const int kbase = z * (LL / 2);
    const int srow = t >> 3, sc8 = t & 7;   // staging map: 4 uint4/thread

    // prologue: issue tile-0 staging loads first (overlap Km/MMD/Q-conv)
    uint4 sreg[4];
    #pragma unroll
    for (int i = 0; i < 4; i++) {
        const int row = srow + i * 32;
        sreg[i] = *(const uint4*)&KH[((size_t)(bh * LL + kbase + row)) * DH + sc8 * 8];
    }

    if (z == 0) {
        if (t < 64) Km[t] = Kmean[bh * DH + t];
        __syncthreads();
        if (t < 128) {
            const float4* qr = (const float4*)&Qp[((size_t)bh * LL + q0 + t) * DH];
            const float4* km4 = (const float4*)Km;
            float md = 0.f;
            #pragma unroll
            for (int i = 0; i < 16; i++) {
                float4 a = qr[i], b = km4[i];
                md += a.x * b.x + a.y * b.y + a.z * b.z + a.w * b.w;
            }
            MMD[(size_t)bh * LL + q0 + t] = SCALEF * md;
        }
    }

    bf16x8 aH[2][2], aL[2][2];
    #pragma unroll
    for (int mt = 0; mt < 2; mt++) {
        const float* qrp = &Qp[((size_t)bh * LL + q0 + w * 32 + mt * 16 + n16) * DH + quad * 8];
        float v[16];
        *(float4*)&v[0]  = *(const float4*)(qrp);
        *(float4*)&v[4]  = *(const float4*)(qrp + 4);
        *(float4*)&v[8]  = *(const float4*)(qrp + 32);
        *(float4*)&v[12] = *(const float4*)(qrp + 36);
        #pragma unroll
        for (int j = 0; j < 8; j++) {
            ushort h0 = f32_to_bf16_rn(v[j]);
            aH[mt][0][j] = (short)h0;
            aL[mt][0][j] = (short)f32_to_bf16_rn(v[j] - bf16_to_f32(h0));
            ushort h1 = f32_to_bf16_rn(v[8 + j]);
            aH[mt][1][j] = (short)h1;
            aL[mt][1][j] = (short)f32_to_bf16_rn(v[8 + j] - bf16_to_f32(h1));
        }
    }

    f32x4 maxv[2] = {{-3.4e38f, -3.4e38f, -3.4e38f, -3.4e38f},
                     {-3.4e38f, -3.4e38f, -3.4e38f, -3.4e38f}};

    for (int tile = 0; tile < 8; tile++) {
        // write staged tile to LDS
        #pragma unroll
        for (int i = 0; i < 4; i++) {
            const int row = srow + i * 32;
            *(uint4*)&KS[row * 72 + sc8 * 8] = sreg[i];
        }
        __syncthreads();
        // prefetch next tile (overlaps MFMA below)
        if (tile < 7) {
            const int kt0 = kbase + (tile + 1) * 128;
            #pragma unroll
            for (int i = 0; i < 4; i++) {
                const int row = srow + i * 32;
                sreg[i] = *(const uint4*)&KH[((size_t)(bh * LL + kt0 + row)) * DH + sc8 * 8];
            }
        }

        for (int ktl = 0; ktl < 128; ktl += 16) {
            const ushort* bp = &KS[(size_t)(ktl + n16) * 72 + quad * 8];
            bf16x8 bH0 = *(const bf16x8*)(bp);
            bf16x8 bH1 = *(const bf16x8*)(bp + 32);
            #pragma unroll
            for (int mt = 0; mt < 2; mt++) {
                f32x4 acc = {0.f, 0.f, 0.f, 0.f};
                acc = __builtin_amdgcn_mfma_f32_16x16x32_bf16(aH[mt][0], bH0, acc, 0, 0, 0);
                acc = __builtin_amdgcn_mfma_f32_16x16x32_bf16(aH[mt][1], bH1, acc, 0, 0, 0);
                acc = __builtin_amdgcn_mfma_f32_16x16x32_bf16(aL[mt][0], bH0, acc, 0, 0, 0);
                acc = __builtin_amdgcn_mfma_f32_16x16x32_bf16(aL[mt][1], bH1, acc, 0, 0, 0);
                maxv[mt][0] = fmaxf(maxv[mt][0], acc[0]);
                maxv[mt][1] = fmaxf(maxv[mt][1], acc[1]);
                maxv[mt][2] = fmaxf(maxv[mt][2], acc[2]);
                maxv[mt][3] = fmaxf(maxv[mt][3], acc[3]);
            }
        }
        __syncthreads();
    }

    #pragma unroll
    for (int off = 1; off < 16; off <<= 1)
        #pragma unroll
        for (int mt = 0; mt < 2; mt++)
            #pragma unroll
            for (int r = 0; r < 4; r++)
                maxv[mt][r] = fmaxf(maxv[mt][r], __shfl_xor(maxv[mt][r], off));

    if (n16 == 0) {
        #pragma unroll
        for (int mt = 0; mt < 2; mt++)
            #pragma unroll
            for (int r = 0; r < 4; r++) {
                int lq = w * 32 + mt * 16 + quad * 4 + r;
                MP[((size_t)z * BH + bh) * LL + q0 + lq] = SCALEF * maxv[mt][r];
            }
    }
}

// ---------------------------------------------------------------------------
// Top-64 candidate pool via 3-level radix select. (unchanged)
// ---------------------------------------------------------------------------
__global__ __launch_bounds__(256) void topk_radix(const float* __restrict__ MP,
                                                  const float* __restrict__ MMD,
                                                  int* __restrict__ out_idx) {
    __shared__ unsigned hist[4096];
    __shared__ unsigned segc[256];
    __shared__ unsigned suf[256];
    __shared__ int sb1, sc1, sb2;
    __shared__ int ncnt;
    const int bh = blockIdx.x;
    const int t  = threadIdx.x;

    unsigned key[8];
    #pragma unroll
    for (int i = 0; i < 8; i++) {
        size_t q = (size_t)i * 256 + t;
        float v = fmaxf(MP[(size_t)bh * LL + q], MP[((size_t)BH + bh) * LL + q])
                  - MMD[(size_t)bh * LL + q];
        unsigned u = __float_as_uint(v);
        key[i] = (u & 0x80000000u) ? ~u : (u | 0x80000000u);
    }

    #pragma unroll
    for (int i = 0; i < 16; i++) hist[t * 16 + i] = 0;
    if (t == 0) ncnt = 0;
    __syncthreads();
    #pragma unroll
    for (int i = 0; i < 8; i++) atomicAdd(&hist[key[i] >> 20], 1u);
    __syncthreads();
    unsigned s = 0;
    #pragma unroll
    for (int i = 0; i < 16; i++) s += hist[t * 16 + i];
    segc[t] = s;
    __syncthreads();
    if (t == 0) {
        unsigned run = 0;
        for (int i = 255; i >= 0; i--) { suf[i] = run; run += segc[i]; }
    }
    __syncthreads();
    if (suf[t] < NCAND && suf[t] + segc[t] >= NCAND) {
        unsigned c = suf[t];
        for (int j = 15; j >= 0; j--) {
            int b = t * 16 + j;
            if (c + hist[b] >= NCAND) { sb1 = b; sc1 = (int)c; break; }
            c += hist[b];
        }
    }
    __syncthreads();
    const unsigned b1 = (unsigned)sb1;
    const int c1 = sc1;

    #pragma unroll
    for (int i = 0; i < 16; i++) hist[t * 16 + i] = 0;
    __syncthreads();
    #pragma unroll
    for (int i = 0; i < 8; i++)
        if ((key[i] >> 20) == b1) atomicAdd(&hist[(key[i] >> 8) & 0xfffu], 1u);
    __syncthreads();
    s = 0;
    #pragma unroll
    for (int i = 0; i < 16; i++) s += hist[t * 16 + i];
    segc[t] = s;
    __syncthreads();
    if (t == 0) {
        unsigned run = 0;
        for (int i = 255; i >= 0; i--) { suf[i] = run; run += segc[i]; }
    }
    __syncthreads();
    const int need2 = NCAND - c1;
    if ((int)suf[t] < need2 && (int)(suf[t] + segc[t]) >= need2) {
        unsigned c = suf[t];
        for (int j = 15; j >= 0; j--) {
            int b = t * 16 + j;
            if ((int)(c + hist[b]) >= need2) { sb2 = b; break; }
            c += hist[b];
        }
    }
    __syncthreads();
    const unsigned b2 = (unsigned)sb2;

    #pragma unroll
    for (int i = 0; i < 8; i++)
        if ((key[i] >> 20) > b1) {
            int p = atomicAdd(&ncnt, 1);
            out_idx[bh * NCAND + p] = i * 256 + t;
        }
    __syncthreads();
    #pragma unroll
    for (int i = 0; i < 8; i++)
        if ((key[i] >> 20) == b1 && ((key[i] >> 8) & 0xfffu) > b2) {
            int p = atomicAdd(&ncnt, 1);
            out_idx[bh * NCAND + p] = i * 256 + t;
        }
    __syncthreads();
    #pragma unroll
    for (int i = 0; i < 8; i++)
        if ((key[i] >> 20) == b1 && ((key[i] >> 8) & 0xfffu) == b2) {
            int p = atomicAdd(&ncnt, 1);
            if (p < NCAND) out_idx[bh * NCAND + p] = i * 256 + t;
        }
}

// ---------------------------------------------------------------------------
// Exact refinement phase 1: per-chunk fp32 max-dot for all 64 candidates.
// ---------------------------------------------------------------------------
__global__ __launch_bounds__(256) void exact_partial(const float* __restrict__ Qp,
                                                     const float* __restrict__ Kp,
                                                     const int* __restrict__ CAND,
                                                     float* __restrict__ EMP) {
    __shared__ float Qs[64][65];
    __shared__ float Ks[64][65];
    __shared__ int   cidx[64];
    const int bh = blockIdx.y;
    const int chunk = blockIdx.x;
    const int t = threadIdx.x;
    const int tx = t & 15, ty = t >> 4;

    if (t < 64) cidx[t] = CAND[bh * NCAND + t];
    __syncthreads();
    #pragma unroll
    for (int i = 0; i < 4; i++) {
        int f = i * 256 + t;
        int row = f >> 4, c4 = f & 15;
        const float4 v = *(const float4*)&Qp[((size_t)bh * LL + cidx[row]) * DH + c4 * 4];
        *(float4*)&Qs[row][c4 * 4] = v;
    }

    float mx[4] = {-3.4e38f, -3.4e38f, -3.4e38f, -3.4e38f};

    for (int kt = 0; kt < 4; kt++) {
        __syncthreads();
        #pragma unroll
        for (int i = 0; i < 4; i++) {
            int f = i * 256 + t;
            int row = f >> 4, c4 = f & 15;
            const float4 v = *(const float4*)&Kp[((size_t)(bh * LL + chunk * 256 + kt * 64 + row)) * DH + c4 * 4];
            *(float4*)&Ks[row][c4 * 4] = v;
        }
        __syncthreads();
        float acc[4][4] = {};
        #pragma unroll 8
        for (int dd = 0; dd < 64; dd++) {
            float a[4], b[4];
            #pragma unroll
            for (int i = 0; i < 4; i++) a[i] = Qs[ty * 4 + i][dd];
            #pragma unroll
            for (int j = 0; j < 4; j++) b[j] = Ks[tx * 4 + j][dd];
            #pragma unroll
            for (int i = 0; i < 4; i++)
                #pragma unroll
                for (int j = 0; j < 4; j++) acc[i][j] += a[i] * b[j];
        }
        #pragma unroll
        for (int i = 0; i < 4; i++)
            #pragma unroll
            for (int j = 0; j < 4; j++) mx[i] = fmaxf(mx[i], acc[i][j]);
    }

    #pragma unroll
    for (int off = 1; off < 16; off <<= 1)
        #pragma unroll
        for (int i = 0; i < 4; i++)
            mx[i] = fmaxf(mx[i], __shfl_xor(mx[i], off));

    if (tx == 0) {
        #pragma unroll
        for (int i = 0; i < 4; i++)
            EMP[((size_t)bh * NCAND + ty * 4 + i) * 8 + chunk] = mx[i];
    }
}

// ---------------------------------------------------------------------------
// Exact refinement phase 2 + final top-38. (unchanged)
// ---------------------------------------------------------------------------
__global__ __launch_bounds__(64) void select_kernel(const float* __restrict__ EMP,
                                                    const int* __restrict__ CAND,
                                                    const float* __restrict__ Qp,
                                                    const float* __restrict__ Kmean,
                                                    int* __restrict__ TIDX) {
    __shared__ float Km[64];
    const int bh = blockIdx.x;
    const int t  = threadIdx.x;
    Km[t] = Kmean[bh * DH + t];
    __syncthreads();

    const int qi = CAND[bh * NCAND + t];
    float mx = -3.4e38f;
    #pragma unroll
    for (int c = 0; c < 8; c++) mx = fmaxf(mx, EMP[((size_t)bh * NCAND + t) * 8 + c]);

    const float4* qr = (const float4*)&Qp[((size_t)bh * LL + qi) * DH];
    const float4* km4 = (const float4*)Km;
    float md = 0.f;
    #pragma unroll
    for (int i = 0; i < 16; i++) {
        float4 a = qr[i], b = km4[i];
        md += a.x * b.x + a.y * b.y + a.z * b.z + a.w * b.w;
    }
    float v = SCALEF * mx - SCALEF * md;

    for (int it = 0; it < KTOP; it++) {
        float bv = v; int bq = qi;
        #pragma unroll
        for (int off = 1; off < 64; off <<= 1) {
            float ov = __shfl_xor(bv, off);
            int   oq = __shfl_xor(bq, off);
            if (ov > bv || (ov == bv && oq < bq)) { bv = ov; bq = oq; }
        }
        if (t == 0) TIDX[bh * KTOP + it] = bq;
        if (qi == bq) v = -3.4e38f;
    }
}

// ---------------------------------------------------------------------------
// Sparse attention, phase 1: flash split-K MFMA partials. (unchanged)
// ---------------------------------------------------------------------------
__global__ __launch_bounds__(256) void sparse_partial(const float* __restrict__ Qp,
                                                      const ushort* __restrict__ KH,
                                                      const float* __restrict__ Vp,
                                                      const int* __restrict__ TIDX,
                                                      float* __restrict__ OPART,
                                                      float* __restrict__ MPART,
                                                      float* __restrict__ LPART) {
    __shared__ float sc[QPAD * SCS];
    __shared__ unsigned int Vhl[CHK * VST];
    const int bh = blockIdx.y;
    const int ck = blockIdx.x;
    const int k0 = ck * CHK;
    const int t = threadIdx.x;
    const int w = t >> 6, lane = t & 63;
    const int quad = lane >> 4, n16 = lane & 15;
    const int mt = w;

    #pragma unroll
    for (int i = 0; i < 8; i++) {
        int e = i * 256 + t;
        int key = e >> 4, c4 = e & 15;
        const float4 v = *(const float4*)&Vp[((size_t)(bh * LL + k0 + key)) * DH + c4 * 4];
        uint4 p;
        p.x = pack_hl(v.x); p.y = pack_hl(v.y);
        p.z = pack_hl(v.z); p.w = pack_hl(v.w);
        *(uint4*)&Vhl[key * VST + c4 * 4] = p;
    }

    if (mt < 3) {
        bf16x8 aH[2], aL[2];
        {
            int q = mt * 16 + n16;
            int qq = q < KTOP ? q : (KTOP - 1);
            const float* qp = &Qp[((size_t)bh * LL + TIDX[bh * KTOP + qq]) * DH];
            #pragma unroll
            for (int kf = 0; kf < 2; kf++) {
                float v[8];
                *(float4*)&v[0] = *(const float4*)(qp + kf * 32 + quad * 8);
                *(float4*)&v[4] = *(const float4*)(qp + kf * 32 + quad * 8 + 4);
                #pragma unroll
                for (int j = 0; j < 8; j++) {
                    ushort h = f32_to_bf16_rn(v[j]);
                    aH[kf][j] = (short)h;
                    aL[kf][j] = (short)f32_to_bf16_rn(v[j] - bf16_to_f32(h));
                }
            }
        }
        #pragma unroll
        for (int nt = 0; nt < 8; nt++) {
            f32x4 acc = {0.f, 0.f, 0.f, 0.f};
            #pragma unroll
            for (int kf = 0; kf < 2; kf++) {
                bf16x8 b = *(const bf16x8*)&KH[((size_t)(bh * LL + k0 + nt * 16 + n16)) * DH + kf * 32 + quad * 8];
                acc = __builtin_amdgcn_mfma_f32_16x16x32_bf16(aH[kf], b, acc, 0, 0, 0);
                acc = __builtin_amdgcn_mfma_f32_16x16x32_bf16(aL[kf], b, acc, 0, 0, 0);
            }
            #pragma unroll
            for (int r = 0; r < 4; r++)
                sc[(mt * 16 + quad * 4 + r) * SCS + nt * 16 + n16] = acc[r];
        }
    }
    __syncthreads();

    for (int row = w; row < KTOP; row += 4) {
        float v0 = sc[row * SCS + lane];
        float v1 = sc[row * SCS + 64 + lane];
        float m = fmaxf(v0, v1);
        #pragma unroll
        for (int off = 1; off < 64; off <<= 1)
            m = fmaxf(m, __shfl_xor(m, off));
        const float ms = m * SCALEF;
        float e0 = __expf(v0 * SCALEF - ms);
        float e1 = __expf(v1 * SCALEF - ms);
        float l = e0 + e1;
        #pragma unroll
        for (int off = 1; off < 64; off <<= 1)
            l += __shfl_xor(l, off);
        sc[row * SCS + lane]      = e0;
        sc[row * SCS + 64 + lane] = e1;
        if (lane == 0) {
            MPART[((size_t)ck * BH + bh) * KTOP + row] = ms;
            LPART[((size_t)ck * BH + bh) * KTOP + row] = l;
        }
    }
    __syncthreads();

    if (mt < 3) {
        f32x4 acc[4] = {};
        #pragma unroll
        for (int kf = 0; kf < 4; kf++) {
            bf16x8 ph, pl;
            {
                const float* pp = &sc[(mt * 16 + n16) * SCS + kf * 32 + quad * 8];
                float v[8];
                *(float4*)&v[0] = *(const float4*)(pp);
                *(float4*)&v[4] = *(const float4*)(pp + 4);
                #pragma unroll
                for (int j = 0; j < 8; j++) {
                    ushort h = f32_to_bf16_rn(v[j]);
                    ph[j] = (short)h;
                    pl[j] = (short)f32_to_bf16_rn(v[j] - bf16_to_f32(h));
                }
            }
            #pragma unroll
            for (int nt = 0; nt < 4; nt++) {
                unsigned int u[8];
                #pragma unroll
                for (int j = 0; j < 8; j++)
                    u[j] = Vhl[(kf * 32 + quad * 8 + j) * VST + nt * 16 + n16];
                bf16x8 vh, vl;
                #pragma unroll
                for (int j = 0; j < 8; j++) {
                    vh[j] = (short)(u[j] & 0xffffu);
                    vl[j] = (short)(u[j] >> 16);
                }
                acc[nt] = __builtin_amdgcn_mfma_f32_16x16x32_bf16(ph, vh, acc[nt], 0, 0, 0);
                acc[nt] = __builtin_amdgcn_mfma_f32_16x16x32_bf16(ph, vl, acc[nt], 0, 0, 0);
                acc[nt] = __builtin_amdgcn_mfma_f32_16x16x32_bf16(pl, vh, acc[nt], 0, 0, 0);
            }
        }
        #pragma unroll
        for (int nt = 0; nt < 4; nt++)
            #pragma unroll
            for (int r = 0; r < 4; r++) {
                int q = mt * 16 + quad * 4 + r;
                if (q < KTOP)
                    OPART[(((size_t)ck * BH + bh) * KTOP + q) * DH + nt * 16 + n16] = acc[nt][r];
            }
    }
}

// ---------------------------------------------------------------------------
extern "C" void kernel_launch(void* const* d_in, const int* in_sizes, int n_in,
                              void* d_out, int out_size, void* d_ws, size_t ws_size,
                              hipStream_t stream) {
    const float* x  = (const float*)d_in[0];
    const float* Wq = (const float*)d_in[1];
    const float* bq = (const float*)d_in[2];
    const float* Wk = (const float*)d_in[3];
    const float* bk = (const float*)d_in[4];
    const float* Wv = (const float*)d_in[5];
    const float* bv = (const float*)d_in[6];
    const float* Wo = (const float*)d_in[7];
    const float* bo = (const float*)d_in[8];
    float* out = (float*)d_out;

    float* ws = (float*)d_ws;
    const size_t QSZ = (size_t)BH * LL * DH;   // 4,194,304 elements
    float* Qp    = ws;
    float* Kp    = ws + QSZ;
    float* Vp    = ws + 2 * QSZ;
    float* MMD   = ws + 3 * QSZ;               // BH*L
    float* KMEAN = MMD + (size_t)BH * LL;
    float* VMEAN = KMEAN + BH * DH;
    int*   CAND  = (int*)(VMEAN + BH * DH);    // BH*NCAND
    int*   TIDX  = CAND + BH * NCAND;          // BH*KTOP
    float* EMP   = (float*)(TIDX + BH * KTOP); // BH*NCAND*8
    float* MEANP = EMP + (size_t)BH * NCAND * 8;  // 64*16*64
    float* MP    = MEANP + 65536;              // 2*BH*LL
    float* BASE  = MP + (size_t)2 * BH * LL;   // BB*DD = 2048
    ushort* WTH  = (ushort*)(ws + 3 * QSZ + 786432);   // 3 x 512x512 bf16 hi
    ushort* WTL  = WTH + (size_t)3 * DD * DD;
    ushort* XH   = WTL + (size_t)3 * DD * DD;          // x split hi
    ushort* XL   = XH + QSZ;
    ushort* KH   = XL + QSZ;                           // K split hi
    float* OPART = (float*)(KH + QSZ);                 // NSP*BH*KTOP*DH
    float* MPART = OPART + (size_t)NSP * BH * KTOP * DH;
    float* LPART = MPART + (size_t)NSP * BH * KTOP;

    split_wT<<<dim3(16, 16, 3), 256, 0, stream>>>(Wq, Wk, Wv, WTH, WTL);
    split_x<<<(int)(QSZ / 1024), 256, 0, stream>>>(x, XH, XL);

    // fused QKV projection, BK=64, reg-dbuf pipeline: grid (24, 64)
    mfma_gemm_qkv<<<dim3(24, 64), 256, 0, stream>>>(XH, XL, WTH, WTL,
                                                    bq, bk, bv, Qp, Kp, Vp, KH);

    mean_partial<<<dim3(BH, 2, 16), 256, 0, stream>>>(Kp, Vp, MEANP);
    mean_reduce<<<dim3(BH, 2), 64, 0, stream>>>(MEANP, KMEAN, VMEAN);

    base_kernel<<<BB, 256, 0, stream>>>(VMEAN, Wo, bo, BASE);
    broadcast_base<<<(int)(QSZ / 1024), 256, 0, stream>>>(BASE, out);

    mfma_stats<<<dim3(16, BH, 2), 256, 0, stream>>>(Qp, KH, KMEAN, MP, MMD);

    topk_radix<<<BH, 256, 0, stream>>>(MP, MMD, CAND);

    exact_partial<<<dim3(8, BH), 256, 0, stream>>>(Qp, Kp, CAND, EMP);

    select_kernel<<<BH, 64, 0, stream>>>(EMP, CAND, Qp, KMEAN, TIDX);

    sparse_partial<<<dim3(NSP, BH), 256, 0, stream>>>(Qp, KH, Vp, TIDX, OPART, MPART, LPART);

    scatter_kernel<<<dim3(KTOP, BH), 256, 0, stream>>>(OPART, MPART, LPART, VMEAN,
                                                       TIDX, Wo, out);
}

// Round 12
// 358.342 us; speedup vs baseline: 1.0055x; 1.0055x over previous
//
#include <hip/hip_runtime.h>

#define BB   4
#define LL   2048
#define DD   512
#define HH   8
#define DH   64
#define BH   32          // B*H
#define KTOP 38
#define NCAND 64         // approx-M candidate pool for exact refinement
#define SCALEF 0.125f    // 1/sqrt(64)

// sparse flash split-K params
#define NSP  16          // key chunks
#define CHK  128         // keys per chunk (LL/NSP)
#define QPAD 48          // queries padded to 3 m-tiles
#define SCS  132         // sc row stride (floats)
#define VST  66          // Vhl row stride (uints)

typedef __attribute__((ext_vector_type(8))) short bf16x8;
typedef __attribute__((ext_vector_type(8))) unsigned short ushort8;
typedef __attribute__((ext_vector_type(4))) float f32x4;

__device__ __forceinline__ ushort f32_to_bf16_rn(float x) {
    unsigned u = __float_as_uint(x);
    u += 0x7fffu + ((u >> 16) & 1u);
    return (ushort)(u >> 16);
}
__device__ __forceinline__ float bf16_to_f32(ushort h) {
    return __uint_as_float(((unsigned)h) << 16);
}
__device__ __forceinline__ unsigned int pack_hl(float x) {
    ushort h = f32_to_bf16_rn(x);
    ushort l = f32_to_bf16_rn(x - bf16_to_f32(h));
    return ((unsigned int)l << 16) | (unsigned int)h;
}

// ---------------------------------------------------------------------------
// Elementwise split: fp32 array -> bf16 hi + lo arrays (layout-preserving).
// ---------------------------------------------------------------------------
__global__ __launch_bounds__(256) void split_x(const float* __restrict__ X,
                                               ushort* __restrict__ XH,
                                               ushort* __restrict__ XL) {
    const size_t c = (size_t)blockIdx.x * 256 + threadIdx.x;
    const float4 v = *(const float4*)&X[c * 4];
    ushort4 h, l;
    h.x = f32_to_bf16_rn(v.x); l.x = f32_to_bf16_rn(v.x - bf16_to_f32(h.x));
    h.y = f32_to_bf16_rn(v.y); l.y = f32_to_bf16_rn(v.y - bf16_to_f32(h.y));
    h.z = f32_to_bf16_rn(v.z); l.z = f32_to_bf16_rn(v.z - bf16_to_f32(h.z));
    h.w = f32_to_bf16_rn(v.w); l.w = f32_to_bf16_rn(v.w - bf16_to_f32(h.w));
    *(ushort4*)&XH[c * 4] = h;
    *(ushort4*)&XL[c * 4] = l;
}

// ---------------------------------------------------------------------------
// Prep: transpose + split 3 weight matrices (Wq,Wk,Wv) into [n][k] bf16 hi/lo.
// ---------------------------------------------------------------------------
__global__ __launch_bounds__(256) void split_wT(const float* __restrict__ W0,
                                                const float* __restrict__ W1,
                                                const float* __restrict__ W2,
                                                ushort* __restrict__ WTH,
                                                ushort* __restrict__ WTL) {
    __shared__ float tile[32][33];
    const int z = blockIdx.z;
    const float* W = (z == 0) ? W0 : (z == 1) ? W1 : W2;
    ushort* oh = WTH + (size_t)z * DD * DD;
    ushort* ol = WTL + (size_t)z * DD * DD;
    const int n0 = blockIdx.x * 32, k0 = blockIdx.y * 32;
    const int t = threadIdx.x;
    const int r = t >> 5, c = t & 31;
    #pragma unroll
    for (int i = 0; i < 4; i++)
        tile[r + i * 8][c] = W[(size_t)(k0 + r + i * 8) * DD + n0 + c];
    __syncthreads();
    #pragma unroll
    for (int i = 0; i < 4; i++) {
        int row = r + i * 8;
        float v = tile[c][row];
        ushort h = f32_to_bf16_rn(v);
        oh[(size_t)(n0 + row) * DD + k0 + c] = h;
        ol[(size_t)(n0 + row) * DD + k0 + c] = f32_to_bf16_rn(v - bf16_to_f32(h));
    }
}

// ---------------------------------------------------------------------------
// FUSED QKV projection GEMM, BK=64, register-double-buffered pipeline.
// K-loop FULLY UNROLLED so buffer indices are compile-time constants --
// R11's runtime `cur = k & 1` dynamic-indexed a register array, which the
// compiler demoted to scratch (WRITE_SIZE 59 -> 195 MB). MFMA chain order
// identical to R10.
// ---------------------------------------------------------------------------
__global__ __launch_bounds__(256) void mfma_gemm_qkv(const ushort* __restrict__ AH,
                                                     const ushort* __restrict__ AL,
                                                     const ushort* __restrict__ BTH,
                                                     const ushort* __restrict__ BTL,
                                                     const float* __restrict__ bq,
                                                     const float* __restrict__ bk,
                                                     const float* __restrict__ bv,
                                                     float* __restrict__ Qp,
                                                     float* __restrict__ Kp,
                                                     float* __restrict__ Vp,
                                                     ushort* __restrict__ KH) {
    __shared__ ushort BHs[64 * 72];
    __shared__ ushort BLs[64 * 72];

    const int t = threadIdx.x;
    const int w = t >> 6, lane = t & 63;
    const int quad = lane >> 4, n16 = lane & 15;
    const int row0 = blockIdx.y * 128;
    const int n0   = blockIdx.x * 64;        // 0..1472
    const int z    = n0 >> 9;                // 0=Q 1=K 2=V
    const int nloc0 = n0 & 511;

    const float* bias = (z == 0) ? bq : (z == 1) ? bk : bv;
    float* Y          = (z == 0) ? Qp : (z == 1) ? Kp : Vp;

    f32x4 acc[2][4] = {};

    size_t arow_off[2];
    #pragma unroll
    for (int mt = 0; mt < 2; mt++)
        arow_off[mt] = (size_t)(row0 + w * 32 + mt * 16 + n16) * DD;

    const size_t bbase = (size_t)z * DD * DD;
    const int srow = t >> 3, sc8 = t & 7;    // B staging map: 2 uint4/thread

    // ---- prologue: load step-0 B stage regs + A frags ----
    uint4 bregH[2], bregL[2];
    #pragma unroll
    for (int i = 0; i < 2; i++) {
        const int row = srow + i * 32;
        const size_t goff = bbase + (size_t)(nloc0 + row) * DD + sc8 * 8;
        bregH[i] = *(const uint4*)&BTH[goff];
        bregL[i] = *(const uint4*)&BTL[goff];
    }
    bf16x8 ah[2][2][2], al[2][2][2];        // [buf][mt][kf] -- indices static under full unroll
    #pragma unroll
    for (int mt = 0; mt < 2; mt++)
        #pragma unroll
        for (int kf = 0; kf < 2; kf++) {
            size_t off = arow_off[mt] + kf * 32 + quad * 8;
            ah[0][mt][kf] = *(const bf16x8*)&AH[off];
            al[0][mt][kf] = *(const bf16x8*)&AL[off];
        }

    #pragma unroll
    for (int k = 0; k < 8; k++) {            // k0 = k*64  (FULL UNROLL)
        const int cur = k & 1, nxt = cur ^ 1;
        // write staged B regs to LDS
        #pragma unroll
        for (int i = 0; i < 2; i++) {
            const int row = srow + i * 32;
            *(uint4*)&BHs[row * 72 + sc8 * 8] = bregH[i];
            *(uint4*)&BLs[row * 72 + sc8 * 8] = bregL[i];
        }
        __syncthreads();

        // prefetch next step (overlaps MFMA below)
        if (k < 7) {
            const int kn = (k + 1) * 64;
            #pragma unroll
            for (int i = 0; i < 2; i++) {
                const int row = srow + i * 32;
                const size_t goff = bbase + (size_t)(nloc0 + row) * DD + kn + sc8 * 8;
                bregH[i] = *(const uint4*)&BTH[goff];
                bregL[i] = *(const uint4*)&BTL[goff];
            }
            #pragma unroll
            for (int mt = 0; mt < 2; mt++)
                #pragma unroll
                for (int kf = 0; kf < 2; kf++) {
                    size_t off = arow_off[mt] + kn + kf * 32 + quad * 8;
                    ah[nxt][mt][kf] = *(const bf16x8*)&AH[off];
                    al[nxt][mt][kf] = *(const bf16x8*)&AL[off];
                }
        }

        // MFMA (same chain order as R10)
        #pragma unroll
        for (int kf = 0; kf < 2; kf++)
            #pragma unroll
            for (int nt = 0; nt < 4; nt++) {
                int boff = (nt * 16 + n16) * 72 + kf * 32 + quad * 8;
                bf16x8 bh = *(const bf16x8*)&BHs[boff];
                bf16x8 bl = *(const bf16x8*)&BLs[boff];
                #pragma unroll
                for (int mt = 0; mt < 2; mt++) {
                    acc[mt][nt] = __builtin_amdgcn_mfma_f32_16x16x32_bf16(ah[cur][mt][kf], bh, acc[mt][nt], 0, 0, 0);
                    acc[mt][nt] = __builtin_amdgcn_mfma_f32_16x16x32_bf16(ah[cur][mt][kf], bl, acc[mt][nt], 0, 0, 0);
                    acc[mt][nt] = __builtin_amdgcn_mfma_f32_16x16x32_bf16(al[cur][mt][kf], bh, acc[mt][nt], 0, 0, 0);
                }
            }
        __syncthreads();
    }

    #pragma unroll
    for (int mt = 0; mt < 2; mt++)
        #pragma unroll
        for (int nt = 0; nt < 4; nt++) {
            const int c = nloc0 + nt * 16 + n16;
            const float bvv = bias[c];
            const int h = c >> 6, dh = c & 63;
            #pragma unroll
            for (int r = 0; r < 4; r++) {
                int R = row0 + w * 32 + mt * 16 + quad * 4 + r;
                int b = R >> 11, l = R & 2047;
                float v = acc[mt][nt][r] + bvv;
                size_t off = (((size_t)(b * HH + h)) * LL + l) * DH + dh;
                Y[off] = v;
                if (z == 1) KH[off] = f32_to_bf16_rn(v);
            }
        }
}

// ---------------------------------------------------------------------------
// Mean phase 1: partial sums. grid (BH, 2, 16); block sums 128 rows.
// ---------------------------------------------------------------------------
__global__ __launch_bounds__(256) void mean_partial(const float* __restrict__ Kp,
                                                    const float* __restrict__ Vp,
                                                    float* __restrict__ partial) {
    __shared__ float red[256];
    const int bh = blockIdx.x;
    const int srcI = blockIdx.y;
    const int z  = blockIdx.z;
    const float* src = srcI ? Vp : Kp;
    const int t = threadIdx.x;
    const int d = t & 63, ch = t >> 6;
    const int l0 = z * 128 + ch * 32;
    float s = 0.f;
    for (int l = l0; l < l0 + 32; l++)
        s += src[((size_t)bh * LL + l) * DH + d];
    red[t] = s;
    __syncthreads();
    if (t < 64)
        partial[((size_t)((bh * 2 + srcI) * 16 + z)) * 64 + t] =
            red[t] + red[t + 64] + red[t + 128] + red[t + 192];
}

// ---------------------------------------------------------------------------
// Mean phase 2: fold 16 partials. grid (BH, 2), 64 thr.
// ---------------------------------------------------------------------------
__global__ __launch_bounds__(64) void mean_reduce(const float* __restrict__ partial,
                                                  float* __restrict__ Kmean,
                                                  float* __restrict__ Vmean) {
    const int bh = blockIdx.x;
    const int srcI = blockIdx.y;
    const int t  = threadIdx.x;
    float s = 0.f;
    #pragma unroll
    for (int z = 0; z < 16; z++)
        s += partial[((size_t)((bh * 2 + srcI) * 16 + z)) * 64 + t];
    float* dst = srcI ? Vmean : Kmean;
    dst[bh * DH + t] = s * (1.0f / LL);
}

// ---------------------------------------------------------------------------
// base[b] = sum_h Vmean[b,h] @ Wo_h + bo  (fp32 exact). Grid (BB), 256 thr.
// ---------------------------------------------------------------------------
__global__ __launch_bounds__(256) void base_kernel(const float* __restrict__ Vmean,
                                                   const float* __restrict__ Wo,
                                                   const float* __restrict__ bo,
                                                   float* __restrict__ BASE) {
    __shared__ float vm[512];
    const int b = blockIdx.x;
    const int t = threadIdx.x;
    vm[t]       = Vmean[b * 512 + t];
    vm[t + 256] = Vmean[b * 512 + t + 256];
    __syncthreads();
    #pragma unroll
    for (int cc = 0; cc < 2; cc++) {
        const int c = cc * 256 + t;
        float s = 0.f;
        for (int k = 0; k < 512; k++) s += vm[k] * Wo[(size_t)k * 512 + c];
        BASE[b * 512 + c] = s + bo[c];
    }
}

// ---------------------------------------------------------------------------
// Broadcast base rows into out. 4096 blocks x 256 thr, float4 each.
// ---------------------------------------------------------------------------
__global__ __launch_bounds__(256) void broadcast_base(const float* __restrict__ BASE,
                                                      float* __restrict__ out) {
    const size_t f = ((size_t)blockIdx.x * 256 + threadIdx.x) * 4;
    const int b = (int)(f >> 20);            // / (2048*512)
    const int c = (int)(f & 511);
    *(float4*)&out[f] = *(const float4*)&BASE[b * 512 + c];
}

// ---------------------------------------------------------------------------
// FUSED combine+scatter: per (bh,q) fold the 16 split-K partials (softmax
// merge), subtract Vmean, and scatter (corr @ Wo_h) into out via atomicAdd.
// ---------------------------------------------------------------------------
__global__ __launch_bounds__(256) void scatter_kernel(const float* __restrict__ OPART,
                                                      const float* __restrict__ MPART,
                                                      const float* __restrict__ LPART,
                                                      const float* __restrict__ Vmean,
                                                      const int* __restrict__ TIDX,
                                                      const float* __restrict__ Wo,
                                                      float* __restrict__ out) {
    __shared__ float cr[64];
    const int q = blockIdx.x, bh = blockIdx.y;
    const int b = bh >> 3, h = bh & 7;
    const int t = threadIdx.x;
    if (t < 64) {
        float m[NSP];
        float mx = -3.4e38f;
        #pragma unroll
        for (int c = 0; c < NSP; c++) {
            m[c] = MPART[((size_t)c * BH + bh) * KTOP + q];
            mx = fmaxf(mx, m[c]);
        }
        float L = 0.f;
        #pragma unroll
        for (int c = 0; c < NSP; c++) {
            m[c] = __expf(m[c] - mx);
            L += m[c] * LPART[((size_t)c * BH + bh) * KTOP + q];
        }
        const float inv = 1.0f / L;
        float o = 0.f;
        #pragma unroll
        for (int c = 0; c < NSP; c++)
            o += m[c] * OPART[(((size_t)c * BH + bh) * KTOP + q) * DH + t];
        cr[t] = o * inv - Vmean[bh * DH + t];
    }
    __syncthreads();
    const int l = TIDX[bh * KTOP + q];
    #pragma unroll
    for (int cc = 0; cc < 2; cc++) {
        const int c = cc * 256 + t;
        float s = 0.f;
        #pragma unroll
        for (int d = 0; d < 64; d++) s += cr[d] * Wo[(size_t)(h * 64 + d) * 512 + c];
        atomicAdd(&out[((size_t)b * LL + l) * DD + c], s);
    }
}

// ---------------------------------------------------------------------------
// Approx M, split-K, register-prefetch pipelined K staging (static sreg
// indices -- no spill). Grid (16, BH, 2).
// ---------------------------------------------------------------------------
__global__ __launch_bounds__(256) void mfma_stats(const float* __restrict__ Qp,
                                                  const ushort* __restrict__ KH,
                                                  const float* __restrict__ Kmean,
                                                  float* __restrict__ MP,
                                                  float* __restrict__ MMD) {
    __shared__ ushort KS[128 * 72];
    __shared__ float  Km[64];

    const int bh = blockIdx.y;
    const int q0 = blockIdx.x * 128;
    const int z  = blockIdx.z;
    const int t    = threadIdx.x;
    const int w    = t >> 6;
    const int lane = t & 63;
    const int quad = lane >> 4;
    const int n16  = lane & 15;
    const int kbase = z * (LL / 2);
    const int srow = t >> 3, sc8 = t & 7;   // staging map: 4 uint4/thread

    // prologue: issue tile-0 staging loads first (overlap Km/MMD/Q-conv)
    uint4 sreg[4];
    #pragma unroll
    for (int i = 0; i < 4; i++) {
        const int row = srow + i * 32;
        sreg[i] = *(const uint4*)&KH[((size_t)(bh * LL + kbase + row)) * DH + sc8 * 8];
    }

    if (z == 0) {
        if (t < 64) Km[t] = Kmean[bh * DH + t];
        __syncthreads();
        if (t < 128) {
            const float4* qr = (const float4*)&Qp[((size_t)bh * LL + q0 + t) * DH];
            const float4* km4 = (const float4*)Km;
            float md = 0.f;
            #pragma unroll
            for (int i = 0; i < 16; i++) {
                float4 a = qr[i], b = km4[i];
                md += a.x * b.x + a.y * b.y + a.z * b.z + a.w * b.w;
            }
            MMD[(size_t)bh * LL + q0 + t] = SCALEF * md;
        }
    }

    bf16x8 aH[2][2], aL[2][2];
    #pragma unroll
    for (int mt = 0; mt < 2; mt++) {
        const float* qrp = &Qp[((size_t)bh * LL + q0 + w * 32 + mt * 16 + n16) * DH + quad * 8];
        float v[16];
        *(float4*)&v[0]  = *(const float4*)(qrp);
        *(float4*)&v[4]  = *(const float4*)(qrp + 4);
        *(float4*)&v[8]  = *(const float4*)(qrp + 32);
        *(float4*)&v[12] = *(const float4*)(qrp + 36);
        #pragma unroll
        for (int j = 0; j < 8; j++) {
            ushort h0 = f32_to_bf16_rn(v[j]);
            aH[mt][0][j] = (short)h0;
            aL[mt][0][j] = (short)f32_to_bf16_rn(v[j] - bf16_to_f32(h0));
            ushort h1 = f32_to_bf16_rn(v[8 + j]);
            aH[mt][1][j] = (short)h1;
            aL[mt][1][j] = (short)f32_to_bf16_rn(v[8 + j] - bf16_to_f32(h1));
        }
    }

    f32x4 maxv[2] = {{-3.4e38f, -3.4e38f, -3.4e38f, -3.4e38f},
                     {-3.4e38f, -3.4e38f, -3.4e38f, -3.4e38f}};

    for (int tile = 0; tile < 8; tile++) {
        #pragma unroll
        for (int i = 0; i < 4; i++) {
            const int row = srow + i * 32;
            *(uint4*)&KS[row * 72 + sc8 * 8] = sreg[i];
        }
        __syncthreads();
        if (tile < 7) {
            const int kt0 = kbase + (tile + 1) * 128;
            #pragma unroll
            for (int i = 0; i < 4; i++) {
                const int row = srow + i * 32;
                sreg[i] = *(const uint4*)&KH[((size_t)(bh * LL + kt0 + row)) * DH + sc8 * 8];
            }
        }

        for (int ktl = 0; ktl < 128; ktl += 16) {
            const ushort* bp = &KS[(size_t)(ktl + n16) * 72 + quad * 8];
            bf16x8 bH0 = *(const bf16x8*)(bp);
            bf16x8 bH1 = *(const bf16x8*)(bp + 32);
            #pragma unroll
            for (int mt = 0; mt < 2; mt++) {
                f32x4 acc = {0.f, 0.f, 0.f, 0.f};
                acc = __builtin_amdgcn_mfma_f32_16x16x32_bf16(aH[mt][0], bH0, acc, 0, 0, 0);
                acc = __builtin_amdgcn_mfma_f32_16x16x32_bf16(aH[mt][1], bH1, acc, 0, 0, 0);
                acc = __builtin_amdgcn_mfma_f32_16x16x32_bf16(aL[mt][0], bH0, acc, 0, 0, 0);
                acc = __builtin_amdgcn_mfma_f32_16x16x32_bf16(aL[mt][1], bH1, acc, 0, 0, 0);
                maxv[mt][0] = fmaxf(maxv[mt][0], acc[0]);
                maxv[mt][1] = fmaxf(maxv[mt][1], acc[1]);
                maxv[mt][2] = fmaxf(maxv[mt][2], acc[2]);
                maxv[mt][3] = fmaxf(maxv[mt][3], acc[3]);
            }
        }
        __syncthreads();
    }

    #pragma unroll
    for (int off = 1; off < 16; off <<= 1)
        #pragma unroll
        for (int mt = 0; mt < 2; mt++)
            #pragma unroll
            for (int r = 0; r < 4; r++)
                maxv[mt][r] = fmaxf(maxv[mt][r], __shfl_xor(maxv[mt][r], off));

    if (n16 == 0) {
        #pragma unroll
        for (int mt = 0; mt < 2; mt++)
            #pragma unroll
            for (int r = 0; r < 4; r++) {
                int lq = w * 32 + mt * 16 + quad * 4 + r;
                MP[((size_t)z * BH + bh) * LL + q0 + lq] = SCALEF * maxv[mt][r];
            }
    }
}

// ---------------------------------------------------------------------------
// Top-64 candidate pool via 3-level radix select. (unchanged)
// ---------------------------------------------------------------------------
__global__ __launch_bounds__(256) void topk_radix(const float* __restrict__ MP,
                                                  const float* __restrict__ MMD,
                                                  int* __restrict__ out_idx) {
    __shared__ unsigned hist[4096];
    __shared__ unsigned segc[256];
    __shared__ unsigned suf[256];
    __shared__ int sb1, sc1, sb2;
    __shared__ int ncnt;
    const int bh = blockIdx.x;
    const int t  = threadIdx.x;

    unsigned key[8];
    #pragma unroll
    for (int i = 0; i < 8; i++) {
        size_t q = (size_t)i * 256 + t;
        float v = fmaxf(MP[(size_t)bh * LL + q], MP[((size_t)BH + bh) * LL + q])
                  - MMD[(size_t)bh * LL + q];
        unsigned u = __float_as_uint(v);
        key[i] = (u & 0x80000000u) ? ~u : (u | 0x80000000u);
    }

    #pragma unroll
    for (int i = 0; i < 16; i++) hist[t * 16 + i] = 0;
    if (t == 0) ncnt = 0;
    __syncthreads();
    #pragma unroll
    for (int i = 0; i < 8; i++) atomicAdd(&hist[key[i] >> 20], 1u);
    __syncthreads();
    unsigned s = 0;
    #pragma unroll
    for (int i = 0; i < 16; i++) s += hist[t * 16 + i];
    segc[t] = s;
    __syncthreads();
    if (t == 0) {
        unsigned run = 0;
        for (int i = 255; i >= 0; i--) { suf[i] = run; run += segc[i]; }
    }
    __syncthreads();
    if (suf[t] < NCAND && suf[t] + segc[t] >= NCAND) {
        unsigned c = suf[t];
        for (int j = 15; j >= 0; j--) {
            int b = t * 16 + j;
            if (c + hist[b] >= NCAND) { sb1 = b; sc1 = (int)c; break; }
            c += hist[b];
        }
    }
    __syncthreads();
    const unsigned b1 = (unsigned)sb1;
    const int c1 = sc1;

    #pragma unroll
    for (int i = 0; i < 16; i++) hist[t * 16 + i] = 0;
    __syncthreads();
    #pragma unroll
    for (int i = 0; i < 8; i++)
        if ((key[i] >> 20) == b1) atomicAdd(&hist[(key[i] >> 8) & 0xfffu], 1u);
    __syncthreads();
    s = 0;
    #pragma unroll
    for (int i = 0; i < 16; i++) s += hist[t * 16 + i];
    segc[t] = s;
    __syncthreads();
    if (t == 0) {
        unsigned run = 0;
        for (int i = 255; i >= 0; i--) { suf[i] = run; run += segc[i]; }
    }
    __syncthreads();
    const int need2 = NCAND - c1;
    if ((int)suf[t] < need2 && (int)(suf[t] + segc[t]) >= need2) {
        unsigned c = suf[t];
        for (int j = 15; j >= 0; j--) {
            int b = t * 16 + j;
            if ((int)(c + hist[b]) >= need2) { sb2 = b; break; }
            c += hist[b];
        }
    }
    __syncthreads();
    const unsigned b2 = (unsigned)sb2;

    #pragma unroll
    for (int i = 0; i < 8; i++)
        if ((key[i] >> 20) > b1) {
            int p = atomicAdd(&ncnt, 1);
            out_idx[bh * NCAND + p] = i * 256 + t;
        }
    __syncthreads();
    #pragma unroll
    for (int i = 0; i < 8; i++)
        if ((key[i] >> 20) == b1 && ((key[i] >> 8) & 0xfffu) > b2) {
            int p = atomicAdd(&ncnt, 1);
            out_idx[bh * NCAND + p] = i * 256 + t;
        }
    __syncthreads();
    #pragma unroll
    for (int i = 0; i < 8; i++)
        if ((key[i] >> 20) == b1 && ((key[i] >> 8) & 0xfffu) == b2) {
            int p = atomicAdd(&ncnt, 1);
            if (p < NCAND) out_idx[bh * NCAND + p] = i * 256 + t;
        }
}

// ---------------------------------------------------------------------------
// Exact refinement phase 1: per-chunk fp32 max-dot for all 64 candidates.
// ---------------------------------------------------------------------------
__global__ __launch_bounds__(256) void exact_partial(const float* __restrict__ Qp,
                                                     const float* __restrict__ Kp,
                                                     const int* __restrict__ CAND,
                                                     float* __restrict__ EMP) {
    __shared__ float Qs[64][65];
    __shared__ float Ks[64][65];
    __shared__ int   cidx[64];
    const int bh = blockIdx.y;
    const int chunk = blockIdx.x;
    const int t = threadIdx.x;
    const int tx = t & 15, ty = t >> 4;

    if (t < 64) cidx[t] = CAND[bh * NCAND + t];
    __syncthreads();
    #pragma unroll
    for (int i = 0; i < 4; i++) {
        int f = i * 256 + t;
        int row = f >> 4, c4 = f & 15;
        const float4 v = *(const float4*)&Qp[((size_t)bh * LL + cidx[row]) * DH + c4 * 4];
        *(float4*)&Qs[row][c4 * 4] = v;
    }

    float mx[4] = {-3.4e38f, -3.4e38f, -3.4e38f, -3.4e38f};

    for (int kt = 0; kt < 4; kt++) {
        __syncthreads();
        #pragma unroll
        for (int i = 0; i < 4; i++) {
            int f = i * 256 + t;
            int row = f >> 4, c4 = f & 15;
            const float4 v = *(const float4*)&Kp[((size_t)(bh * LL + chunk * 256 + kt * 64 + row)) * DH + c4 * 4];
            *(float4*)&Ks[row][c4 * 4] = v;
        }
        __syncthreads();
        float acc[4][4] = {};
        #pragma unroll 8
        for (int dd = 0; dd < 64; dd++) {
            float a[4], b[4];
            #pragma unroll
            for (int i = 0; i < 4; i++) a[i] = Qs[ty * 4 + i][dd];
            #pragma unroll
            for (int j = 0; j < 4; j++) b[j] = Ks[tx * 4 + j][dd];
            #pragma unroll
            for (int i = 0; i < 4; i++)
                #pragma unroll
                for (int j = 0; j < 4; j++) acc[i][j] += a[i] * b[j];
        }
        #pragma unroll
        for (int i = 0; i < 4; i++)
            #pragma unroll
            for (int j = 0; j < 4; j++) mx[i] = fmaxf(mx[i], acc[i][j]);
    }

    #pragma unroll
    for (int off = 1; off < 16; off <<= 1)
        #pragma unroll
        for (int i = 0; i < 4; i++)
            mx[i] = fmaxf(mx[i], __shfl_xor(mx[i], off));

    if (tx == 0) {
        #pragma unroll
        for (int i = 0; i < 4; i++)
            EMP[((size_t)bh * NCAND + ty * 4 + i) * 8 + chunk] = mx[i];
    }
}

// ---------------------------------------------------------------------------
// Exact refinement phase 2 + final top-38. (unchanged)
// ---------------------------------------------------------------------------
__global__ __launch_bounds__(64) void select_kernel(const float* __restrict__ EMP,
                                                    const int* __restrict__ CAND,
                                                    const float* __restrict__ Qp,
                                                    const float* __restrict__ Kmean,
                                                    int* __restrict__ TIDX) {
    __shared__ float Km[64];
    const int bh = blockIdx.x;
    const int t  = threadIdx.x;
    Km[t] = Kmean[bh * DH + t];
    __syncthreads();

    const int qi = CAND[bh * NCAND + t];
    float mx = -3.4e38f;
    #pragma unroll
    for (int c = 0; c < 8; c++) mx = fmaxf(mx, EMP[((size_t)bh * NCAND + t) * 8 + c]);

    const float4* qr = (const float4*)&Qp[((size_t)bh * LL + qi) * DH];
    const float4* km4 = (const float4*)Km;
    float md = 0.f;
    #pragma unroll
    for (int i = 0; i < 16; i++) {
        float4 a = qr[i], b = km4[i];
        md += a.x * b.x + a.y * b.y + a.z * b.z + a.w * b.w;
    }
    float v = SCALEF * mx - SCALEF * md;

    for (int it = 0; it < KTOP; it++) {
        float bv = v; int bq = qi;
        #pragma unroll
        for (int off = 1; off < 64; off <<= 1) {
            float ov = __shfl_xor(bv, off);
            int   oq = __shfl_xor(bq, off);
            if (ov > bv || (ov == bv && oq < bq)) { bv = ov; bq = oq; }
        }
        if (t == 0) TIDX[bh * KTOP + it] = bq;
        if (qi == bq) v = -3.4e38f;
    }
}

// ---------------------------------------------------------------------------
// Sparse attention, phase 1: flash split-K MFMA partials. (unchanged)
// ---------------------------------------------------------------------------
__global__ __launch_bounds__(256) void sparse_partial(const float* __restrict__ Qp,
                                                      const ushort* __restrict__ KH,
                                                      const float* __restrict__ Vp,
                                                      const int* __restrict__ TIDX,
                                                      float* __restrict__ OPART,
                                                      float* __restrict__ MPART,
                                                      float* __restrict__ LPART) {
    __shared__ float sc[QPAD * SCS];
    __shared__ unsigned int Vhl[CHK * VST];
    const int bh = blockIdx.y;
    const int ck = blockIdx.x;
    const int k0 = ck * CHK;
    const int t = threadIdx.x;
    const int w = t >> 6, lane = t & 63;
    const int quad = lane >> 4, n16 = lane & 15;
    const int mt = w;

    #pragma unroll
    for (int i = 0; i < 8; i++) {
        int e = i * 256 + t;
        int key = e >> 4, c4 = e & 15;
        const float4 v = *(const float4*)&Vp[((size_t)(bh * LL + k0 + key)) * DH + c4 * 4];
        uint4 p;
        p.x = pack_hl(v.x); p.y = pack_hl(v.y);
        p.z = pack_hl(v.z); p.w = pack_hl(v.w);
        *(uint4*)&Vhl[key * VST + c4 * 4] = p;
    }

    if (mt < 3) {
        bf16x8 aH[2], aL[2];
        {
            int q = mt * 16 + n16;
            int qq = q < KTOP ? q : (KTOP - 1);
            const float* qp = &Qp[((size_t)bh * LL + TIDX[bh * KTOP + qq]) * DH];
            #pragma unroll
            for (int kf = 0; kf < 2; kf++) {
                float v[8];
                *(float4*)&v[0] = *(const float4*)(qp + kf * 32 + quad * 8);
                *(float4*)&v[4] = *(const float4*)(qp + kf * 32 + quad * 8 + 4);
                #pragma unroll
                for (int j = 0; j < 8; j++) {
                    ushort h = f32_to_bf16_rn(v[j]);
                    aH[kf][j] = (short)h;
                    aL[kf][j] = (short)f32_to_bf16_rn(v[j] - bf16_to_f32(h));
                }
            }
        }
        #pragma unroll
        for (int nt = 0; nt < 8; nt++) {
            f32x4 acc = {0.f, 0.f, 0.f, 0.f};
            #pragma unroll
            for (int kf = 0; kf < 2; kf++) {
                bf16x8 b = *(const bf16x8*)&KH[((size_t)(bh * LL + k0 + nt * 16 + n16)) * DH + kf * 32 + quad * 8];
                acc = __builtin_amdgcn_mfma_f32_16x16x32_bf16(aH[kf], b, acc, 0, 0, 0);
                acc = __builtin_amdgcn_mfma_f32_16x16x32_bf16(aL[kf], b, acc, 0, 0, 0);
            }
            #pragma unroll
            for (int r = 0; r < 4; r++)
                sc[(mt * 16 + quad * 4 + r) * SCS + nt * 16 + n16] = acc[r];
        }
    }
    __syncthreads();

    for (int row = w; row < KTOP; row += 4) {
        float v0 = sc[row * SCS + lane];
        float v1 = sc[row * SCS + 64 + lane];
        float m = fmaxf(v0, v1);
        #pragma unroll
        for (int off = 1; off < 64; off <<= 1)
            m = fmaxf(m, __shfl_xor(m, off));
        const float ms = m * SCALEF;
        float e0 = __expf(v0 * SCALEF - ms);
        float e1 = __expf(v1 * SCALEF - ms);
        float l = e0 + e1;
        #pragma unroll
        for (int off = 1; off < 64; off <<= 1)
            l += __shfl_xor(l, off);
        sc[row * SCS + lane]      = e0;
        sc[row * SCS + 64 + lane] = e1;
        if (lane == 0) {
            MPART[((size_t)ck * BH + bh) * KTOP + row] = ms;
            LPART[((size_t)ck * BH + bh) * KTOP + row] = l;
        }
    }
    __syncthreads();

    if (mt < 3) {
        f32x4 acc[4] = {};
        #pragma unroll
        for (int kf = 0; kf < 4; kf++) {
            bf16x8 ph, pl;
            {
                const float* pp = &sc[(mt * 16 + n16) * SCS + kf * 32 + quad * 8];
                float v[8];
                *(float4*)&v[0] = *(const float4*)(pp);
                *(float4*)&v[4] = *(const float4*)(pp + 4);
                #pragma unroll
                for (int j = 0; j < 8; j++) {
                    ushort h = f32_to_bf16_rn(v[j]);
                    ph[j] = (short)h;
                    pl[j] = (short)f32_to_bf16_rn(v[j] - bf16_to_f32(h));
                }
            }
            #pragma unroll
            for (int nt = 0; nt < 4; nt++) {
                unsigned int u[8];
                #pragma unroll
                for (int j = 0; j < 8; j++)
                    u[j] = Vhl[(kf * 32 + quad * 8 + j) * VST + nt * 16 + n16];
                bf16x8 vh, vl;
                #pragma unroll
                for (int j = 0; j < 8; j++) {
                    vh[j] = (short)(u[j] & 0xffffu);
                    vl[j] = (short)(u[j] >> 16);
                }
                acc[nt] = __builtin_amdgcn_mfma_f32_16x16x32_bf16(ph, vh, acc[nt], 0, 0, 0);
                acc[nt] = __builtin_amdgcn_mfma_f32_16x16x32_bf16(ph, vl, acc[nt], 0, 0, 0);
                acc[nt] = __builtin_amdgcn_mfma_f32_16x16x32_bf16(pl, vh, acc[nt], 0, 0, 0);
            }
        }
        #pragma unroll
        for (int nt = 0; nt < 4; nt++)
            #pragma unroll
            for (int r = 0; r < 4; r++) {
                int q = mt * 16 + quad * 4 + r;
                if (q < KTOP)
                    OPART[(((size_t)ck * BH + bh) * KTOP + q) * DH + nt * 16 + n16] = acc[nt][r];
            }
    }
}

// ---------------------------------------------------------------------------
extern "C" void kernel_launch(void* const* d_in, const int* in_sizes, int n_in,
                              void* d_out, int out_size, void* d_ws, size_t ws_size,
                              hipStream_t stream) {
    const float* x  = (const float*)d_in[0];
    const float* Wq = (const float*)d_in[1];
    const float* bq = (const float*)d_in[2];
    const float* Wk = (const float*)d_in[3];
    const float* bk = (const float*)d_in[4];
    const float* Wv = (const float*)d_in[5];
    const float* bv = (const float*)d_in[6];
    const float* Wo = (const float*)d_in[7];
    const float* bo = (const float*)d_in[8];
    float* out = (float*)d_out;

    float* ws = (float*)d_ws;
    const size_t QSZ = (size_t)BH * LL * DH;   // 4,194,304 elements
    float* Qp    = ws;
    float* Kp    = ws + QSZ;
    float* Vp    = ws + 2 * QSZ;
    float* MMD   = ws + 3 * QSZ;               // BH*L
    float* KMEAN = MMD + (size_t)BH * LL;
    float* VMEAN = KMEAN + BH * DH;
    int*   CAND  = (int*)(VMEAN + BH * DH);    // BH*NCAND
    int*   TIDX  = CAND + BH * NCAND;          // BH*KTOP
    float* EMP   = (float*)(TIDX + BH * KTOP); // BH*NCAND*8
    float* MEANP = EMP + (size_t)BH * NCAND * 8;  // 64*16*64
    float* MP    = MEANP + 65536;              // 2*BH*LL
    float* BASE  = MP + (size_t)2 * BH * LL;   // BB*DD = 2048
    ushort* WTH  = (ushort*)(ws + 3 * QSZ + 786432);   // 3 x 512x512 bf16 hi
    ushort* WTL  = WTH + (size_t)3 * DD * DD;
    ushort* XH   = WTL + (size_t)3 * DD * DD;          // x split hi
    ushort* XL   = XH + QSZ;
    ushort* KH   = XL + QSZ;                           // K split hi
    float* OPART = (float*)(KH + QSZ);                 // NSP*BH*KTOP*DH
    float* MPART = OPART + (size_t)NSP * BH * KTOP * DH;
    float* LPART = MPART + (size_t)NSP * BH * KTOP;

    split_wT<<<dim3(16, 16, 3), 256, 0, stream>>>(Wq, Wk, Wv, WTH, WTL);
    split_x<<<(int)(QSZ / 1024), 256, 0, stream>>>(x, XH, XL);

    // fused QKV projection, BK=64, reg-dbuf pipeline (fully unrolled K-loop)
    mfma_gemm_qkv<<<dim3(24, 64), 256, 0, stream>>>(XH, XL, WTH, WTL,
                                                    bq, bk, bv, Qp, Kp, Vp, KH);

    mean_partial<<<dim3(BH, 2, 16), 256, 0, stream>>>(Kp, Vp, MEANP);
    mean_reduce<<<dim3(BH, 2), 64, 0, stream>>>(MEANP, KMEAN, VMEAN);

    base_kernel<<<BB, 256, 0, stream>>>(VMEAN, Wo, bo, BASE);
    broadcast_base<<<(int)(QSZ / 1024), 256, 0, stream>>>(BASE, out);

    mfma_stats<<<dim3(16, BH, 2), 256, 0, stream>>>(Qp, KH, KMEAN, MP, MMD);

    topk_radix<<<BH, 256, 0, stream>>>(MP, MMD, CAND);

    exact_partial<<<dim3(8, BH), 256, 0, stream>>>(Qp, Kp, CAND, EMP);

    select_kernel<<<BH, 64, 0, stream>>>(EMP, CAND, Qp, KMEAN, TIDX);

    sparse_partial<<<dim3(NSP, BH), 256, 0, stream>>>(Qp, KH, Vp, TIDX, OPART, MPART, LPART);

    scatter_kernel<<<dim3(KTOP, BH), 256, 0, stream>>>(OPART, MPART, LPART, VMEAN,
                                                       TIDX, Wo, out);
}

// Round 13
// 298.360 us; speedup vs baseline: 1.2077x; 1.2010x over previous
//
#include <hip/hip_runtime.h>

#define BB   4
#define LL   2048
#define DD   512
#define HH   8
#define DH   64
#define BH   32          // B*H
#define KTOP 38
#define NCAND 64         // approx-M candidate pool for exact refinement
#define SCALEF 0.125f    // 1/sqrt(64)

// sparse flash split-K params
#define NSP  16          // key chunks
#define CHK  128         // keys per chunk (LL/NSP)
#define QPAD 48          // queries padded to 3 m-tiles
#define SCS  132         // sc row stride (floats)
#define VST  66          // Vhl row stride (uints)

typedef __attribute__((ext_vector_type(8))) short bf16x8;
typedef __attribute__((ext_vector_type(8))) unsigned short ushort8;
typedef __attribute__((ext_vector_type(4))) float f32x4;

__device__ __forceinline__ ushort f32_to_bf16_rn(float x) {
    unsigned u = __float_as_uint(x);
    u += 0x7fffu + ((u >> 16) & 1u);
    return (ushort)(u >> 16);
}
__device__ __forceinline__ float bf16_to_f32(ushort h) {
    return __uint_as_float(((unsigned)h) << 16);
}
__device__ __forceinline__ unsigned int pack_hl(float x) {
    ushort h = f32_to_bf16_rn(x);
    ushort l = f32_to_bf16_rn(x - bf16_to_f32(h));
    return ((unsigned int)l << 16) | (unsigned int)h;
}

// ---------------------------------------------------------------------------
// Elementwise split: fp32 array -> bf16 hi + lo arrays (layout-preserving).
// ---------------------------------------------------------------------------
__global__ __launch_bounds__(256) void split_x(const float* __restrict__ X,
                                               ushort* __restrict__ XH,
                                               ushort* __restrict__ XL) {
    const size_t c = (size_t)blockIdx.x * 256 + threadIdx.x;
    const float4 v = *(const float4*)&X[c * 4];
    ushort4 h, l;
    h.x = f32_to_bf16_rn(v.x); l.x = f32_to_bf16_rn(v.x - bf16_to_f32(h.x));
    h.y = f32_to_bf16_rn(v.y); l.y = f32_to_bf16_rn(v.y - bf16_to_f32(h.y));
    h.z = f32_to_bf16_rn(v.z); l.z = f32_to_bf16_rn(v.z - bf16_to_f32(h.z));
    h.w = f32_to_bf16_rn(v.w); l.w = f32_to_bf16_rn(v.w - bf16_to_f32(h.w));
    *(ushort4*)&XH[c * 4] = h;
    *(ushort4*)&XL[c * 4] = l;
}

// ---------------------------------------------------------------------------
// Prep: transpose + split 4 weight matrices W[k][n] into WT_H/WT_L [n][k] bf16.
// ---------------------------------------------------------------------------
__global__ __launch_bounds__(256) void split_wT(const float* __restrict__ W0,
                                                const float* __restrict__ W1,
                                                const float* __restrict__ W2,
                                                const float* __restrict__ W3,
                                                ushort* __restrict__ WTH,
                                                ushort* __restrict__ WTL) {
    __shared__ float tile[32][33];
    const int z = blockIdx.z;
    const float* W = (z == 0) ? W0 : (z == 1) ? W1 : (z == 2) ? W2 : W3;
    ushort* oh = WTH + (size_t)z * DD * DD;
    ushort* ol = WTL + (size_t)z * DD * DD;
    const int n0 = blockIdx.x * 32, k0 = blockIdx.y * 32;
    const int t = threadIdx.x;
    const int r = t >> 5, c = t & 31;
    #pragma unroll
    for (int i = 0; i < 4; i++)
        tile[r + i * 8][c] = W[(size_t)(k0 + r + i * 8) * DD + n0 + c];
    __syncthreads();
    #pragma unroll
    for (int i = 0; i < 4; i++) {
        int row = r + i * 8;
        float v = tile[c][row];
        ushort h = f32_to_bf16_rn(v);
        oh[(size_t)(n0 + row) * DD + k0 + c] = h;
        ol[(size_t)(n0 + row) * DD + k0 + c] = f32_to_bf16_rn(v - bf16_to_f32(h));
    }
}

// ---------------------------------------------------------------------------
// FUSED QKV projection GEMM, BK=64, simple loop (R10 body — measured 65.3 µs,
// VGPR 64, no scratch spill). Grid (24, 64). B LDS stride-72 rows; A direct
// global->VGPR. No register prefetch: R11/R12 showed the compiler spills the
// A double-buffer to scratch (WRITE_SIZE 59 -> 195 MB) regardless of unroll.
// ---------------------------------------------------------------------------
__global__ __launch_bounds__(256) void mfma_gemm_qkv(const ushort* __restrict__ AH,
                                                     const ushort* __restrict__ AL,
                                                     const ushort* __restrict__ BTH,
                                                     const ushort* __restrict__ BTL,
                                                     const float* __restrict__ bq,
                                                     const float* __restrict__ bk,
                                                     const float* __restrict__ bv,
                                                     float* __restrict__ Qp,
                                                     float* __restrict__ Kp,
                                                     float* __restrict__ Vp,
                                                     ushort* __restrict__ KH) {
    __shared__ ushort BHs[64 * 72];
    __shared__ ushort BLs[64 * 72];

    const int t = threadIdx.x;
    const int w = t >> 6, lane = t & 63;
    const int quad = lane >> 4, n16 = lane & 15;
    const int row0 = blockIdx.y * 128;
    const int n0   = blockIdx.x * 64;        // 0..1472
    const int z    = n0 >> 9;                // 0=Q 1=K 2=V
    const int nloc0 = n0 & 511;

    const float* bias = (z == 0) ? bq : (z == 1) ? bk : bv;
    float* Y          = (z == 0) ? Qp : (z == 1) ? Kp : Vp;

    f32x4 acc[2][4] = {};

    size_t arow_off[2];
    #pragma unroll
    for (int mt = 0; mt < 2; mt++)
        arow_off[mt] = (size_t)(row0 + w * 32 + mt * 16 + n16) * DD;

    const size_t bbase = (size_t)z * DD * DD;

    for (int k0 = 0; k0 < DD; k0 += 64) {
        // stage B: 64 rows x 64 k (hi+lo); 512 uint4 per array, 2 per thread
        #pragma unroll
        for (int i = 0; i < 2; i++) {
            int s = i * 256 + t;
            int row = s >> 3, c8 = s & 7;
            const size_t goff = bbase + (size_t)(nloc0 + row) * DD + k0 + c8 * 8;
            *(uint4*)&BHs[row * 72 + c8 * 8] = *(const uint4*)&BTH[goff];
            *(uint4*)&BLs[row * 72 + c8 * 8] = *(const uint4*)&BTL[goff];
        }
        // A fragments direct from global (2 m-tiles x 2 k-frags)
        bf16x8 ah[2][2], al[2][2];
        #pragma unroll
        for (int mt = 0; mt < 2; mt++)
            #pragma unroll
            for (int kf = 0; kf < 2; kf++) {
                size_t off = arow_off[mt] + k0 + kf * 32 + quad * 8;
                ah[mt][kf] = *(const bf16x8*)&AH[off];
                al[mt][kf] = *(const bf16x8*)&AL[off];
            }
        __syncthreads();

        #pragma unroll
        for (int kf = 0; kf < 2; kf++)
            #pragma unroll
            for (int nt = 0; nt < 4; nt++) {
                int boff = (nt * 16 + n16) * 72 + kf * 32 + quad * 8;
                bf16x8 bh = *(const bf16x8*)&BHs[boff];
                bf16x8 bl = *(const bf16x8*)&BLs[boff];
                #pragma unroll
                for (int mt = 0; mt < 2; mt++) {
                    acc[mt][nt] = __builtin_amdgcn_mfma_f32_16x16x32_bf16(ah[mt][kf], bh, acc[mt][nt], 0, 0, 0);
                    acc[mt][nt] = __builtin_amdgcn_mfma_f32_16x16x32_bf16(ah[mt][kf], bl, acc[mt][nt], 0, 0, 0);
                    acc[mt][nt] = __builtin_amdgcn_mfma_f32_16x16x32_bf16(al[mt][kf], bh, acc[mt][nt], 0, 0, 0);
                }
            }
        __syncthreads();
    }

    #pragma unroll
    for (int mt = 0; mt < 2; mt++)
        #pragma unroll
        for (int nt = 0; nt < 4; nt++) {
            const int c = nloc0 + nt * 16 + n16;
            const float bvv = bias[c];
            const int h = c >> 6, dh = c & 63;
            #pragma unroll
            for (int r = 0; r < 4; r++) {
                int R = row0 + w * 32 + mt * 16 + quad * 4 + r;
                int b = R >> 11, l = R & 2047;
                float v = acc[mt][nt][r] + bvv;
                size_t off = (((size_t)(b * HH + h)) * LL + l) * DH + dh;
                Y[off] = v;
                if (z == 1) KH[off] = f32_to_bf16_rn(v);
            }
        }
}

// ---------------------------------------------------------------------------
// Output GEMM: out = ctx @ Wo + bo. (R9 body)
// ---------------------------------------------------------------------------
__global__ __launch_bounds__(256) void mfma_gemm_out(const ushort* __restrict__ AH,
                                                     const ushort* __restrict__ AL,
                                                     const ushort* __restrict__ BTH,
                                                     const ushort* __restrict__ BTL,
                                                     const float* __restrict__ bias,
                                                     float* __restrict__ Y) {
    __shared__ ushort BHs[64 * 40];
    __shared__ ushort BLs[64 * 40];

    const int t = threadIdx.x;
    const int w = t >> 6, lane = t & 63;
    const int quad = lane >> 4, n16 = lane & 15;
    const int row0 = blockIdx.y * 128;
    const int n0   = blockIdx.x * 64;

    f32x4 acc[2][4] = {};

    size_t arow_off[2];
    #pragma unroll
    for (int mt = 0; mt < 2; mt++) {
        int R = row0 + w * 32 + mt * 16 + n16;
        int b = R >> 11, l = R & 2047;
        arow_off[mt] = ((size_t)b * HH) * LL * DH + (size_t)l * DH;
    }

    const int brow = t >> 2, bc8 = t & 3;

    for (int k0 = 0; k0 < DD; k0 += 32) {
        {
            const size_t goff = (size_t)(n0 + brow) * DD + k0 + bc8 * 8;
            const uint4 vh = *(const uint4*)&BTH[goff];
            const uint4 vl = *(const uint4*)&BTL[goff];
            *(uint4*)&BHs[brow * 40 + bc8 * 8] = vh;
            *(uint4*)&BLs[brow * 40 + bc8 * 8] = vl;
        }
        bf16x8 ah[2], al[2];
        #pragma unroll
        for (int mt = 0; mt < 2; mt++) {
            int k = k0 + quad * 8;
            int h = k >> 6, dh = k & 63;
            size_t off = arow_off[mt] + (size_t)h * LL * DH + dh;
            ah[mt] = *(const bf16x8*)&AH[off];
            al[mt] = *(const bf16x8*)&AL[off];
        }
        __syncthreads();

        bf16x8 bh[4], bl[4];
        #pragma unroll
        for (int nt = 0; nt < 4; nt++) {
            int off = (nt * 16 + n16) * 40 + quad * 8;
            bh[nt] = *(const bf16x8*)&BHs[off];
            bl[nt] = *(const bf16x8*)&BLs[off];
        }
        #pragma unroll
        for (int mt = 0; mt < 2; mt++)
            #pragma unroll
            for (int nt = 0; nt < 4; nt++) {
                acc[mt][nt] = __builtin_amdgcn_mfma_f32_16x16x32_bf16(ah[mt], bh[nt], acc[mt][nt], 0, 0, 0);
                acc[mt][nt] = __builtin_amdgcn_mfma_f32_16x16x32_bf16(ah[mt], bl[nt], acc[mt][nt], 0, 0, 0);
                acc[mt][nt] = __builtin_amdgcn_mfma_f32_16x16x32_bf16(al[mt], bh[nt], acc[mt][nt], 0, 0, 0);
            }
        __syncthreads();
    }

    #pragma unroll
    for (int mt = 0; mt < 2; mt++)
        #pragma unroll
        for (int nt = 0; nt < 4; nt++) {
            const int c = n0 + nt * 16 + n16;
            const float bvv = bias[c];
            #pragma unroll
            for (int r = 0; r < 4; r++) {
                int R = row0 + w * 32 + mt * 16 + quad * 4 + r;
                Y[(size_t)R * DD + c] = acc[mt][nt][r] + bvv;
            }
        }
}

// ---------------------------------------------------------------------------
// Mean phase 1: partial sums. grid (BH, 2, 16); block sums 128 rows.
// ---------------------------------------------------------------------------
__global__ __launch_bounds__(256) void mean_partial(const float* __restrict__ Kp,
                                                    const float* __restrict__ Vp,
                                                    float* __restrict__ partial) {
    __shared__ float red[256];
    const int bh = blockIdx.x;
    const int srcI = blockIdx.y;
    const int z  = blockIdx.z;
    const float* src = srcI ? Vp : Kp;
    const int t = threadIdx.x;
    const int d = t & 63, ch = t >> 6;
    const int l0 = z * 128 + ch * 32;
    float s = 0.f;
    for (int l = l0; l < l0 + 32; l++)
        s += src[((size_t)bh * LL + l) * DH + d];
    red[t] = s;
    __syncthreads();
    if (t < 64)
        partial[((size_t)((bh * 2 + srcI) * 16 + z)) * 64 + t] =
            red[t] + red[t + 64] + red[t + 128] + red[t + 192];
}

// ---------------------------------------------------------------------------
// Mean phase 2: fold 16 partials. grid (BH, 2), 64 thr.
// ---------------------------------------------------------------------------
__global__ __launch_bounds__(64) void mean_reduce(const float* __restrict__ partial,
                                                  float* __restrict__ Kmean,
                                                  float* __restrict__ Vmean) {
    const int bh = blockIdx.x;
    const int srcI = blockIdx.y;
    const int t  = threadIdx.x;
    float s = 0.f;
    #pragma unroll
    for (int z = 0; z < 16; z++)
        s += partial[((size_t)((bh * 2 + srcI) * 16 + z)) * 64 + t];
    float* dst = srcI ? Vmean : Kmean;
    dst[bh * DH + t] = s * (1.0f / LL);
}

// ---------------------------------------------------------------------------
// Approx M, split-K: grid (16, BH, 2). (R9 body)
// ---------------------------------------------------------------------------
__global__ __launch_bounds__(256) void mfma_stats(const float* __restrict__ Qp,
                                                  const ushort* __restrict__ KH,
                                                  const float* __restrict__ Kmean,
                                                  float* __restrict__ MP,
                                                  float* __restrict__ MMD) {
    __shared__ ushort KS[128 * 72];
    __shared__ float  Km[64];

    const int bh = blockIdx.y;
    const int q0 = blockIdx.x * 128;
    const int z  = blockIdx.z;
    const int t    = threadIdx.x;
    const int w    = t >> 6;
    const int lane = t & 63;
    const int quad = lane >> 4;
    const int n16  = lane & 15;

    if (z == 0) {
        if (t < 64) Km[t] = Kmean[bh * DH + t];
        __syncthreads();
        if (t < 128) {
            const float4* qr = (const float4*)&Qp[((size_t)bh * LL + q0 + t) * DH];
            const float4* km4 = (const float4*)Km;
            float md = 0.f;
            #pragma unroll
            for (int i = 0; i < 16; i++) {
                float4 a = qr[i], b = km4[i];
                md += a.x * b.x + a.y * b.y + a.z * b.z + a.w * b.w;
            }
            MMD[(size_t)bh * LL + q0 + t] = SCALEF * md;
        }
    }

    bf16x8 aH[2][2], aL[2][2];
    #pragma unroll
    for (int mt = 0; mt < 2; mt++) {
        const float* qrp = &Qp[((size_t)bh * LL + q0 + w * 32 + mt * 16 + n16) * DH + quad * 8];
        float v[16];
        *(float4*)&v[0]  = *(const float4*)(qrp);
        *(float4*)&v[4]  = *(const float4*)(qrp + 4);
        *(float4*)&v[8]  = *(const float4*)(qrp + 32);
        *(float4*)&v[12] = *(const float4*)(qrp + 36);
        #pragma unroll
        for (int j = 0; j < 8; j++) {
            ushort h0 = f32_to_bf16_rn(v[j]);
            aH[mt][0][j] = (short)h0;
            aL[mt][0][j] = (short)f32_to_bf16_rn(v[j] - bf16_to_f32(h0));
            ushort h1 = f32_to_bf16_rn(v[8 + j]);
            aH[mt][1][j] = (short)h1;
            aL[mt][1][j] = (short)f32_to_bf16_rn(v[8 + j] - bf16_to_f32(h1));
        }
    }

    f32x4 maxv[2] = {{-3.4e38f, -3.4e38f, -3.4e38f, -3.4e38f},
                     {-3.4e38f, -3.4e38f, -3.4e38f, -3.4e38f}};

    const int kbase = z * (LL / 2);
    for (int kt0 = kbase; kt0 < kbase + LL / 2; kt0 += 128) {
        __syncthreads();
        #pragma unroll
        for (int i = 0; i < 4; i++) {
            int f = i * 256 + t;
            int row = f >> 3, c8 = f & 7;
            const uint4 v = *(const uint4*)&KH[((size_t)(bh * LL + kt0 + row)) * DH + c8 * 8];
            *(uint4*)&KS[row * 72 + c8 * 8] = v;
        }
        __syncthreads();

        for (int ktl = 0; ktl < 128; ktl += 16) {
            const ushort* bp = &KS[(size_t)(ktl + n16) * 72 + quad * 8];
            bf16x8 bH0 = *(const bf16x8*)(bp);
            bf16x8 bH1 = *(const bf16x8*)(bp + 32);
            #pragma unroll
            for (int mt = 0; mt < 2; mt++) {
                f32x4 acc = {0.f, 0.f, 0.f, 0.f};
                acc = __builtin_amdgcn_mfma_f32_16x16x32_bf16(aH[mt][0], bH0, acc, 0, 0, 0);
                acc = __builtin_amdgcn_mfma_f32_16x16x32_bf16(aH[mt][1], bH1, acc, 0, 0, 0);
                acc = __builtin_amdgcn_mfma_f32_16x16x32_bf16(aL[mt][0], bH0, acc, 0, 0, 0);
                acc = __builtin_amdgcn_mfma_f32_16x16x32_bf16(aL[mt][1], bH1, acc, 0, 0, 0);
                maxv[mt][0] = fmaxf(maxv[mt][0], acc[0]);
                maxv[mt][1] = fmaxf(maxv[mt][1], acc[1]);
                maxv[mt][2] = fmaxf(maxv[mt][2], acc[2]);
                maxv[mt][3] = fmaxf(maxv[mt][3], acc[3]);
            }
        }
    }

    #pragma unroll
    for (int off = 1; off < 16; off <<= 1)
        #pragma unroll
        for (int mt = 0; mt < 2; mt++)
            #pragma unroll
            for (int r = 0; r < 4; r++)
                maxv[mt][r] = fmaxf(maxv[mt][r], __shfl_xor(maxv[mt][r], off));

    if (n16 == 0) {
        #pragma unroll
        for (int mt = 0; mt < 2; mt++)
            #pragma unroll
            for (int r = 0; r < 4; r++) {
                int lq = w * 32 + mt * 16 + quad * 4 + r;
                MP[((size_t)z * BH + bh) * LL + q0 + lq] = SCALEF * maxv[mt][r];
            }
    }
}

// ---------------------------------------------------------------------------
// Top-64 candidate pool via 3-level radix select. Folds split-K stats:
// M = max(MP0, MP1) - MMD at load.
// ---------------------------------------------------------------------------
__global__ __launch_bounds__(256) void topk_radix(const float* __restrict__ MP,
                                                  const float* __restrict__ MMD,
                                                  int* __restrict__ out_idx) {
    __shared__ unsigned hist[4096];
    __shared__ unsigned segc[256];
    __shared__ unsigned suf[256];
    __shared__ int sb1, sc1, sb2;
    __shared__ int ncnt;
    const int bh = blockIdx.x;
    const int t  = threadIdx.x;

    unsigned key[8];
    #pragma unroll
    for (int i = 0; i < 8; i++) {
        size_t q = (size_t)i * 256 + t;
        float v = fmaxf(MP[(size_t)bh * LL + q], MP[((size_t)BH + bh) * LL + q])
                  - MMD[(size_t)bh * LL + q];
        unsigned u = __float_as_uint(v);
        key[i] = (u & 0x80000000u) ? ~u : (u | 0x80000000u);
    }

    #pragma unroll
    for (int i = 0; i < 16; i++) hist[t * 16 + i] = 0;
    if (t == 0) ncnt = 0;
    __syncthreads();
    #pragma unroll
    for (int i = 0; i < 8; i++) atomicAdd(&hist[key[i] >> 20], 1u);
    __syncthreads();
    unsigned s = 0;
    #pragma unroll
    for (int i = 0; i < 16; i++) s += hist[t * 16 + i];
    segc[t] = s;
    __syncthreads();
    if (t == 0) {
        unsigned run = 0;
        for (int i = 255; i >= 0; i--) { suf[i] = run; run += segc[i]; }
    }
    __syncthreads();
    if (suf[t] < NCAND && suf[t] + segc[t] >= NCAND) {
        unsigned c = suf[t];
        for (int j = 15; j >= 0; j--) {
            int b = t * 16 + j;
            if (c + hist[b] >= NCAND) { sb1 = b; sc1 = (int)c; break; }
            c += hist[b];
        }
    }
    __syncthreads();
    const unsigned b1 = (unsigned)sb1;
    const int c1 = sc1;

    #pragma unroll
    for (int i = 0; i < 16; i++) hist[t * 16 + i] = 0;
    __syncthreads();
    #pragma unroll
    for (int i = 0; i < 8; i++)
        if ((key[i] >> 20) == b1) atomicAdd(&hist[(key[i] >> 8) & 0xfffu], 1u);
    __syncthreads();
    s = 0;
    #pragma unroll
    for (int i = 0; i < 16; i++) s += hist[t * 16 + i];
    segc[t] = s;
    __syncthreads();
    if (t == 0) {
        unsigned run = 0;
        for (int i = 255; i >= 0; i--) { suf[i] = run; run += segc[i]; }
    }
    __syncthreads();
    const int need2 = NCAND - c1;
    if ((int)suf[t] < need2 && (int)(suf[t] + segc[t]) >= need2) {
        unsigned c = suf[t];
        for (int j = 15; j >= 0; j--) {
            int b = t * 16 + j;
            if ((int)(c + hist[b]) >= need2) { sb2 = b; break; }
            c += hist[b];
        }
    }
    __syncthreads();
    const unsigned b2 = (unsigned)sb2;

    #pragma unroll
    for (int i = 0; i < 8; i++)
        if ((key[i] >> 20) > b1) {
            int p = atomicAdd(&ncnt, 1);
            out_idx[bh * NCAND + p] = i * 256 + t;
        }
    __syncthreads();
    #pragma unroll
    for (int i = 0; i < 8; i++)
        if ((key[i] >> 20) == b1 && ((key[i] >> 8) & 0xfffu) > b2) {
            int p = atomicAdd(&ncnt, 1);
            out_idx[bh * NCAND + p] = i * 256 + t;
        }
    __syncthreads();
    #pragma unroll
    for (int i = 0; i < 8; i++)
        if ((key[i] >> 20) == b1 && ((key[i] >> 8) & 0xfffu) == b2) {
            int p = atomicAdd(&ncnt, 1);
            if (p < NCAND) out_idx[bh * NCAND + p] = i * 256 + t;
        }
}

// ---------------------------------------------------------------------------
// Exact refinement phase 1: per-chunk fp32 max-dot for all 64 candidates.
// ---------------------------------------------------------------------------
__global__ __launch_bounds__(256) void exact_partial(const float* __restrict__ Qp,
                                                     const float* __restrict__ Kp,
                                                     const int* __restrict__ CAND,
                                                     float* __restrict__ EMP) {
    __shared__ float Qs[64][65];
    __shared__ float Ks[64][65];
    __shared__ int   cidx[64];
    const int bh = blockIdx.y;
    const int chunk = blockIdx.x;
    const int t = threadIdx.x;
    const int tx = t & 15, ty = t >> 4;

    if (t < 64) cidx[t] = CAND[bh * NCAND + t];
    __syncthreads();
    #pragma unroll
    for (int i = 0; i < 4; i++) {
        int f = i * 256 + t;
        int row = f >> 4, c4 = f & 15;
        const float4 v = *(const float4*)&Qp[((size_t)bh * LL + cidx[row]) * DH + c4 * 4];
        *(float4*)&Qs[row][c4 * 4] = v;
    }

    float mx[4] = {-3.4e38f, -3.4e38f, -3.4e38f, -3.4e38f};

    for (int kt = 0; kt < 4; kt++) {
        __syncthreads();
        #pragma unroll
        for (int i = 0; i < 4; i++) {
            int f = i * 256 + t;
            int row = f >> 4, c4 = f & 15;
            const float4 v = *(const float4*)&Kp[((size_t)(bh * LL + chunk * 256 + kt * 64 + row)) * DH + c4 * 4];
            *(float4*)&Ks[row][c4 * 4] = v;
        }
        __syncthreads();
        float acc[4][4] = {};
        #pragma unroll 8
        for (int dd = 0; dd < 64; dd++) {
            float a[4], b[4];
            #pragma unroll
            for (int i = 0; i < 4; i++) a[i] = Qs[ty * 4 + i][dd];
            #pragma unroll
            for (int j = 0; j < 4; j++) b[j] = Ks[tx * 4 + j][dd];
            #pragma unroll
            for (int i = 0; i < 4; i++)
                #pragma unroll
                for (int j = 0; j < 4; j++) acc[i][j] += a[i] * b[j];
        }
        #pragma unroll
        for (int i = 0; i < 4; i++)
            #pragma unroll
            for (int j = 0; j < 4; j++) mx[i] = fmaxf(mx[i], acc[i][j]);
    }

    #pragma unroll
    for (int off = 1; off < 16; off <<= 1)
        #pragma unroll
        for (int i = 0; i < 4; i++)
            mx[i] = fmaxf(mx[i], __shfl_xor(mx[i], off));

    if (tx == 0) {
        #pragma unroll
        for (int i = 0; i < 4; i++)
            EMP[((size_t)bh * NCAND + ty * 4 + i) * 8 + chunk] = mx[i];
    }
}

// ---------------------------------------------------------------------------
// Exact refinement phase 2 + final top-38.
// ---------------------------------------------------------------------------
__global__ __launch_bounds__(64) void select_kernel(const float* __restrict__ EMP,
                                                    const int* __restrict__ CAND,
                                                    const float* __restrict__ Qp,
                                                    const float* __restrict__ Kmean,
                                                    int* __restrict__ TIDX) {
    __shared__ float Km[64];
    const int bh = blockIdx.x;
    const int t  = threadIdx.x;
    Km[t] = Kmean[bh * DH + t];
    __syncthreads();

    const int qi = CAND[bh * NCAND + t];
    float mx = -3.4e38f;
    #pragma unroll
    for (int c = 0; c < 8; c++) mx = fmaxf(mx, EMP[((size_t)bh * NCAND + t) * 8 + c]);

    const float4* qr = (const float4*)&Qp[((size_t)bh * LL + qi) * DH];
    const float4* km4 = (const float4*)Km;
    float md = 0.f;
    #pragma unroll
    for (int i = 0; i < 16; i++) {
        float4 a = qr[i], b = km4[i];
        md += a.x * b.x + a.y * b.y + a.z * b.z + a.w * b.w;
    }
    float v = SCALEF * mx - SCALEF * md;

    for (int it = 0; it < KTOP; it++) {
        float bv = v; int bq = qi;
        #pragma unroll
        for (int off = 1; off < 64; off <<= 1) {
            float ov = __shfl_xor(bv, off);
            int   oq = __shfl_xor(bq, off);
            if (ov > bv || (ov == bv && oq < bq)) { bv = ov; bq = oq; }
        }
        if (t == 0) TIDX[bh * KTOP + it] = bq;
        if (qi == bq) v = -3.4e38f;
    }
}

// ---------------------------------------------------------------------------
// Fill context (bf16 hi/lo) with per-head V mean.
// ---------------------------------------------------------------------------
__global__ __launch_bounds__(256) void fill_kernel(const float* __restrict__ Vmean,
                                                   ushort* __restrict__ CH,
                                                   ushort* __restrict__ CL) {
    const size_t c = (size_t)blockIdx.x * 256 + threadIdx.x;
    const int d4 = (int)(c & 15) * 4;
    const int bh = (int)(c >> 15);
    const float4 v = *(const float4*)&Vmean[bh * DH + d4];
    ushort4 h, l;
    h.x = f32_to_bf16_rn(v.x); l.x = f32_to_bf16_rn(v.x - bf16_to_f32(h.x));
    h.y = f32_to_bf16_rn(v.y); l.y = f32_to_bf16_rn(v.y - bf16_to_f32(h.y));
    h.z = f32_to_bf16_rn(v.z); l.z = f32_to_bf16_rn(v.z - bf16_to_f32(h.z));
    h.w = f32_to_bf16_rn(v.w); l.w = f32_to_bf16_rn(v.w - bf16_to_f32(h.w));
    *(ushort4*)&CH[c * 4] = h;
    *(ushort4*)&CL[c * 4] = l;
}

// ---------------------------------------------------------------------------
// Sparse attention, phase 1: flash split-K MFMA partials.
// ---------------------------------------------------------------------------
__global__ __launch_bounds__(256) void sparse_partial(const float* __restrict__ Qp,
                                                      const ushort* __restrict__ KH,
                                                      const float* __restrict__ Vp,
                                                      const int* __restrict__ TIDX,
                                                      float* __restrict__ OPART,
                                                      float* __restrict__ MPART,
                                                      float* __restrict__ LPART) {
    __shared__ float sc[QPAD * SCS];
    __shared__ unsigned int Vhl[CHK * VST];
    const int bh = blockIdx.y;
    const int ck = blockIdx.x;
    const int k0 = ck * CHK;
    const int t = threadIdx.x;
    const int w = t >> 6, lane = t & 63;
    const int quad = lane >> 4, n16 = lane & 15;
    const int mt = w;

    #pragma unroll
    for (int i = 0; i < 8; i++) {
        int e = i * 256 + t;
        int key = e >> 4, c4 = e & 15;
        const float4 v = *(const float4*)&Vp[((size_t)(bh * LL + k0 + key)) * DH + c4 * 4];
        uint4 p;
        p.x = pack_hl(v.x); p.y = pack_hl(v.y);
        p.z = pack_hl(v.z); p.w = pack_hl(v.w);
        *(uint4*)&Vhl[key * VST + c4 * 4] = p;
    }

    if (mt < 3) {
        bf16x8 aH[2], aL[2];
        {
            int q = mt * 16 + n16;
            int qq = q < KTOP ? q : (KTOP - 1);
            const float* qp = &Qp[((size_t)bh * LL + TIDX[bh * KTOP + qq]) * DH];
            #pragma unroll
            for (int kf = 0; kf < 2; kf++) {
                float v[8];
                *(float4*)&v[0] = *(const float4*)(qp + kf * 32 + quad * 8);
                *(float4*)&v[4] = *(const float4*)(qp + kf * 32 + quad * 8 + 4);
                #pragma unroll
                for (int j = 0; j < 8; j++) {
                    ushort h = f32_to_bf16_rn(v[j]);
                    aH[kf][j] = (short)h;
                    aL[kf][j] = (short)f32_to_bf16_rn(v[j] - bf16_to_f32(h));
                }
            }
        }
        #pragma unroll
        for (int nt = 0; nt < 8; nt++) {
            f32x4 acc = {0.f, 0.f, 0.f, 0.f};
            #pragma unroll
            for (int kf = 0; kf < 2; kf++) {
                bf16x8 b = *(const bf16x8*)&KH[((size_t)(bh * LL + k0 + nt * 16 + n16)) * DH + kf * 32 + quad * 8];
                acc = __builtin_amdgcn_mfma_f32_16x16x32_bf16(aH[kf], b, acc, 0, 0, 0);
                acc = __builtin_amdgcn_mfma_f32_16x16x32_bf16(aL[kf], b, acc, 0, 0, 0);
            }
            #pragma unroll
            for (int r = 0; r < 4; r++)
                sc[(mt * 16 + quad * 4 + r) * SCS + nt * 16 + n16] = acc[r];
        }
    }
    __syncthreads();

    for (int row = w; row < KTOP; row += 4) {
        float v0 = sc[row * SCS + lane];
        float v1 = sc[row * SCS + 64 + lane];
        float m = fmaxf(v0, v1);
        #pragma unroll
        for (int off = 1; off < 64; off <<= 1)
            m = fmaxf(m, __shfl_xor(m, off));
        const float ms = m * SCALEF;
        float e0 = __expf(v0 * SCALEF - ms);
        float e1 = __expf(v1 * SCALEF - ms);
        float l = e0 + e1;
        #pragma unroll
        for (int off = 1; off < 64; off <<= 1)
            l += __shfl_xor(l, off);
        sc[row * SCS + lane]      = e0;
        sc[row * SCS + 64 + lane] = e1;
        if (lane == 0) {
            MPART[((size_t)ck * BH + bh) * KTOP + row] = ms;
            LPART[((size_t)ck * BH + bh) * KTOP + row] = l;
        }
    }
    __syncthreads();

    if (mt < 3) {
        f32x4 acc[4] = {};
        #pragma unroll
        for (int kf = 0; kf < 4; kf++) {
            bf16x8 ph, pl;
            {
                const float* pp = &sc[(mt * 16 + n16) * SCS + kf * 32 + quad * 8];
                float v[8];
                *(float4*)&v[0] = *(const float4*)(pp);
                *(float4*)&v[4] = *(const float4*)(pp + 4);
                #pragma unroll
                for (int j = 0; j < 8; j++) {
                    ushort h = f32_to_bf16_rn(v[j]);
                    ph[j] = (short)h;
                    pl[j] = (short)f32_to_bf16_rn(v[j] - bf16_to_f32(h));
                }
            }
            #pragma unroll
            for (int nt = 0; nt < 4; nt++) {
                unsigned int u[8];
                #pragma unroll
                for (int j = 0; j < 8; j++)
                    u[j] = Vhl[(kf * 32 + quad * 8 + j) * VST + nt * 16 + n16];
                bf16x8 vh, vl;
                #pragma unroll
                for (int j = 0; j < 8; j++) {
                    vh[j] = (short)(u[j] & 0xffffu);
                    vl[j] = (short)(u[j] >> 16);
                }
                acc[nt] = __builtin_amdgcn_mfma_f32_16x16x32_bf16(ph, vh, acc[nt], 0, 0, 0);
                acc[nt] = __builtin_amdgcn_mfma_f32_16x16x32_bf16(ph, vl, acc[nt], 0, 0, 0);
                acc[nt] = __builtin_amdgcn_mfma_f32_16x16x32_bf16(pl, vh, acc[nt], 0, 0, 0);
            }
        }
        #pragma unroll
        for (int nt = 0; nt < 4; nt++)
            #pragma unroll
            for (int r = 0; r < 4; r++) {
                int q = mt * 16 + quad * 4 + r;
                if (q < KTOP)
                    OPART[(((size_t)ck * BH + bh) * KTOP + q) * DH + nt * 16 + n16] = acc[nt][r];
            }
    }
}

// ---------------------------------------------------------------------------
// Sparse attention, phase 2: split-K softmax merge -> CH/CL rows.
// ---------------------------------------------------------------------------
__global__ __launch_bounds__(256) void sparse_combine(const float* __restrict__ OPART,
                                                      const float* __restrict__ MPART,
                                                      const float* __restrict__ LPART,
                                                      const int* __restrict__ TIDX,
                                                      ushort* __restrict__ CH,
                                                      ushort* __restrict__ CL) {
    __shared__ float wts[NSP][KTOP];
    __shared__ float inv[KTOP];
    __shared__ int   tq[KTOP];
    const int bh = blockIdx.x;
    const int t  = threadIdx.x;
    if (t < KTOP) {
        float m[NSP];
        float mx = -3.4e38f;
        #pragma unroll
        for (int c = 0; c < NSP; c++) {
            m[c] = MPART[((size_t)c * BH + bh) * KTOP + t];
            mx = fmaxf(mx, m[c]);
        }
        float L = 0.f;
        #pragma unroll
        for (int c = 0; c < NSP; c++) {
            float wc = __expf(m[c] - mx);
            wts[c][t] = wc;
            L += wc * LPART[((size_t)c * BH + bh) * KTOP + t];
        }
        inv[t] = 1.0f / L;
        tq[t] = TIDX[bh * KTOP + t];
    }
    __syncthreads();
    for (int i = 0; i < 10; i++) {
        int idx = i * 256 + t;
        if (idx >= KTOP * DH) break;
        int q = idx >> 6, d = idx & 63;
        float o = 0.f;
        #pragma unroll
        for (int c = 0; c < NSP; c++)
            o += wts[c][q] * OPART[(((size_t)c * BH + bh) * KTOP + q) * DH + d];
        float val = o * inv[q];
        size_t off = ((size_t)bh * LL + tq[q]) * DH + d;
        ushort h = f32_to_bf16_rn(val);
        CH[off] = h;
        CL[off] = f32_to_bf16_rn(val - bf16_to_f32(h));
    }
}

// ---------------------------------------------------------------------------
extern "C" void kernel_launch(void* const* d_in, const int* in_sizes, int n_in,
                              void* d_out, int out_size, void* d_ws, size_t ws_size,
                              hipStream_t stream) {
    const float* x  = (const float*)d_in[0];
    const float* Wq = (const float*)d_in[1];
    const float* bq = (const float*)d_in[2];
    const float* Wk = (const float*)d_in[3];
    const float* bk = (const float*)d_in[4];
    const float* Wv = (const float*)d_in[5];
    const float* bv = (const float*)d_in[6];
    const float* Wo = (const float*)d_in[7];
    const float* bo = (const float*)d_in[8];
    float* out = (float*)d_out;

    float* ws = (float*)d_ws;
    const size_t QSZ = (size_t)BH * LL * DH;   // 4,194,304 elements
    float* Qp    = ws;
    float* Kp    = ws + QSZ;
    float* Vp    = ws + 2 * QSZ;
    float* MMD   = ws + 3 * QSZ;               // BH*L  (SCALEF * Q.Kmean)
    float* KMEAN = MMD + (size_t)BH * LL;
    float* VMEAN = KMEAN + BH * DH;
    int*   CAND  = (int*)(VMEAN + BH * DH);    // BH*NCAND
    int*   TIDX  = CAND + BH * NCAND;          // BH*KTOP
    float* EMP   = (float*)(TIDX + BH * KTOP); // BH*NCAND*8
    float* MEANP = EMP + (size_t)BH * NCAND * 8;  // 64*16*64
    float* MP    = MEANP + 65536;              // 2*BH*LL (split-K stats maxes)
    ushort* WTH  = (ushort*)(ws + 3 * QSZ + 524288);   // 4 x 512x512 bf16 hi
    ushort* WTL  = WTH + (size_t)4 * DD * DD;
    ushort* XH   = WTL + (size_t)4 * DD * DD;          // x split hi
    ushort* XL   = XH + QSZ;
    ushort* CH   = XH;                                 // CTX aliases X
    ushort* CL   = XL;
    ushort* KH   = XL + QSZ;                           // K split hi
    float* OPART = (float*)(KH + QSZ);                 // NSP*BH*KTOP*DH
    float* MPART = OPART + (size_t)NSP * BH * KTOP * DH;
    float* LPART = MPART + (size_t)NSP * BH * KTOP;
    const size_t WOFF = (size_t)DD * DD;

    split_wT<<<dim3(16, 16, 4), 256, 0, stream>>>(Wq, Wk, Wv, Wo, WTH, WTL);
    split_x<<<(int)(QSZ / 1024), 256, 0, stream>>>(x, XH, XL);

    // fused QKV projection, BK=64 simple: grid (1536/64, 8192/128) = (24, 64)
    mfma_gemm_qkv<<<dim3(24, 64), 256, 0, stream>>>(XH, XL, WTH, WTL,
                                                    bq, bk, bv, Qp, Kp, Vp, KH);

    mean_partial<<<dim3(BH, 2, 16), 256, 0, stream>>>(Kp, Vp, MEANP);
    mean_reduce<<<dim3(BH, 2), 64, 0, stream>>>(MEANP, KMEAN, VMEAN);

    mfma_stats<<<dim3(16, BH, 2), 256, 0, stream>>>(Qp, KH, KMEAN, MP, MMD);

    topk_radix<<<BH, 256, 0, stream>>>(MP, MMD, CAND);

    exact_partial<<<dim3(8, BH), 256, 0, stream>>>(Qp, Kp, CAND, EMP);

    select_kernel<<<BH, 64, 0, stream>>>(EMP, CAND, Qp, KMEAN, TIDX);

    fill_kernel<<<(int)(QSZ / 1024), 256, 0, stream>>>(VMEAN, CH, CL);

    sparse_partial<<<dim3(NSP, BH), 256, 0, stream>>>(Qp, KH, Vp, TIDX, OPART, MPART, LPART);
    sparse_combine<<<BH, 256, 0, stream>>>(OPART, MPART, LPART, TIDX, CH, CL);

    mfma_gemm_out<<<dim3(8, 64), 256, 0, stream>>>(CH, CL, WTH + 3 * WOFF, WTL + 3 * WOFF, bo, out);
}